// Round 7
// baseline (530.324 us; speedup 1.0000x reference)
//
#include <hip/hip_runtime.h>

typedef unsigned short u16;
typedef __attribute__((ext_vector_type(8))) short bf16x8;
typedef __attribute__((ext_vector_type(4))) float f32x4;

#define NAG 8      // agents per episode
#define FIN 64
#define MDIM 64
#define NACT 10
#define EPG 56     // edges per group = 8*7
#define NTOT 32768 // B*A
#define ABP 72     // padded bf16 A-row (144 B)
#define XLS 296    // u16 stride per agent row of xl/xr (592 B; 148 words ≡ 20 mod 32)
#define XHS 72     // u16 stride per head within a row (144 B; 36 words ≡ 4 mod 32)

// union region (10368 B): phases 2-5 = bf16 xl/xr; phases 6-9 = rz/in/hn/ln (f32)
#define U_XR 2368            // u16 offset of xr (8*296)
#define U_RZ 0               // f32: rz[a][128] (r,z gate pre-sums)
#define U_IN 1024            // f32: inn[a][64]
#define U_HN 1536            // f32: hn[a][64]
#define U_LN 2048            // f32: ln[a][68]

__device__ __forceinline__ float b2f(u16 u) {
  return __uint_as_float(((unsigned int)u) << 16);
}
__device__ __forceinline__ u16 f2b(float f) {
  unsigned int x = __float_as_uint(f);
  unsigned int r = x + 0x7fffu + ((x >> 16) & 1u);   // RNE; values finite
  return (u16)(r >> 16);
}
__device__ __forceinline__ void b8tof(const u16* p, float* o) {
  bf16x8 v = *(const bf16x8*)p;
#pragma unroll
  for (int j = 0; j < 8; j++) o[j] = b2f((u16)v[j]);
}

// ---------- pre-kernel: repack Wl/Wr/W_ih/W_hh into bf16 B-fragment order ----------
__global__ __launch_bounds__(256) void prep_weights(
    const float* __restrict__ Wl, const float* __restrict__ Wr,
    const float* __restrict__ Wih, const float* __restrict__ Whh,
    u16* __restrict__ wsB)
{
  const int idx = blockIdx.x * 256 + threadIdx.x;   // 0 .. 56*2*64-1
  if (idx >= 56 * 2 * 64) return;
  const int L  = idx & 63;
  const int ks = (idx >> 6) & 1;
  const int T  = idx >> 7;
  const float* W; int row0;
  if      (T < 16) { W = Wl;  row0 = T * 16; }
  else if (T < 32) { W = Wr;  row0 = (T - 16) * 16; }
  else if (T < 44) { W = Wih; row0 = (T - 32) * 16; }
  else             { W = Whh; row0 = (T - 44) * 16; }
  const int row = row0 + (L & 15);
  const int k0  = ks * 32 + (L >> 4) * 8;
  u16 v[8];
#pragma unroll
  for (int j = 0; j < 8; j++) v[j] = f2b(W[row * 64 + k0 + j]);
  *(bf16x8*)(wsB + (size_t)idx * 8) = *(bf16x8*)v;
}

__global__ __launch_bounds__(256, 7) void gnn_rnn_kernel(
    const float* __restrict__ x, const float* __restrict__ edge_attr,
    const float* __restrict__ hidden,
    const float* __restrict__ bl, const float* __restrict__ br,
    const float* __restrict__ We, const float* __restrict__ be,
    const float* __restrict__ att, const float* __restrict__ bias_g,
    const float* __restrict__ b_ih, const float* __restrict__ b_hh,
    const float* __restrict__ ln_g, const float* __restrict__ ln_b,
    const float* __restrict__ Wq, const float* __restrict__ bq,
    const u16* __restrict__ wsB,
    float* __restrict__ d_out)
{
  __shared__ __align__(16) char uraw[10368];
  __shared__ __align__(16) u16 s_xb[NAG * ABP];     // x bf16 A-frags
  __shared__ __align__(16) u16 s_hidb[NAG * ABP];   // hidden bf16 A-frags
  __shared__ __align__(16) u16 s_hgb[NAG * ABP];    // h_gnn bf16 A-frags
  __shared__ __align__(16) float s_hid[NAG * MDIM]; // hidden f32 (gate blend)
  __shared__ float s_ea[EPG * 3];
  __shared__ __align__(16) u16 s_blb[256], s_brb[256];
  __shared__ __align__(16) u16 s_w0b[288], s_w1b[288], s_w2b[288], s_beb[288], s_attb[288];
  __shared__ float s_alpha[EPG][4];
  __shared__ float s_bih[192], s_bhh[192];

  u16*   uXL = (u16*)uraw;
  u16*   uXR = (u16*)uraw + U_XR;
  float* uF  = (float*)uraw;

  const int t = threadIdx.x;
  const int b = blockIdx.x;
  const int L = t & 63;        // lane
  const int w = t >> 6;        // wave id 0..3
  const int q = L >> 4;        // quad within wave

  // ---------- Phase 1: stage inputs + small weights ----------
  {
    const float* xb = x + b * (NAG * FIN);
    const float* hb = hidden + b * (NAG * MDIM);
#pragma unroll
    for (int i = t; i < NAG * FIN; i += 256) {
      const int a = i >> 6, m = i & 63;
      s_xb[a * ABP + m] = f2b(xb[i]);
      const float hv = hb[i];
      s_hid[a * MDIM + m] = hv;
      s_hidb[a * ABP + m] = f2b(hv);
    }
    const float* eb = edge_attr + b * (EPG * 3);
    if (t < EPG * 3) s_ea[t] = eb[t];
    s_blb[t] = f2b(bl[t]);  s_brb[t] = f2b(br[t]);
    {
      const int h = t >> 6, d = t & 63, idx = h * XHS + d;
      s_beb[idx]  = f2b(be[t]);
      s_attb[idx] = f2b(att[t]);
      s_w0b[idx]  = f2b(We[t * 3]);
      s_w1b[idx]  = f2b(We[t * 3 + 1]);
      s_w2b[idx]  = f2b(We[t * 3 + 2]);
    }
    if (t < 192)  { s_bih[t] = b_ih[t]; s_bhh[t] = b_hh[t]; }
  }
  __syncthreads();

  // ---------- Phase 2 (MFMA): xl = x@Wl^T+bl, xr = x@Wr^T+br (bf16 out) ----------
  {
    const int arow = L & 7;
    bf16x8 af0 = *(const bf16x8*)&s_xb[arow * ABP + q * 8];
    bf16x8 af1 = *(const bf16x8*)&s_xb[arow * ABP + 32 + q * 8];
    const bf16x8* wsBv = (const bf16x8*)wsB;
#pragma unroll
    for (int i = 0; i < 8; i++) {
      const int T = w * 8 + i;
      f32x4 acc = {0.f, 0.f, 0.f, 0.f};
      acc = __builtin_amdgcn_mfma_f32_16x16x32_bf16(af0, wsBv[(T * 2 + 0) * 64 + L], acc, 0, 0, 0);
      acc = __builtin_amdgcn_mfma_f32_16x16x32_bf16(af1, wsBv[(T * 2 + 1) * 64 + L], acc, 0, 0, 0);
      if (q < 2) {  // valid rows 0..7 in quads 0,1 (agent a = q*4+r)
        const int col = L & 15;
        const int Tm = T & 15;
        const int h = Tm >> 2, d = (Tm & 3) * 16 + col;
        const int gc = Tm * 16 + col;
        if (T < 16) {
          const float bias = b2f(s_blb[gc]);
#pragma unroll
          for (int r = 0; r < 4; r++)
            uXL[(q * 4 + r) * XLS + h * XHS + d] = f2b(acc[r] + bias);
        } else {
          const float bias = b2f(s_brb[gc]);
#pragma unroll
          for (int r = 0; r < 4; r++)
            uXR[(q * 4 + r) * XLS + h * XHS + d] = f2b(acc[r] + bias);
        }
      }
    }
  }
  __syncthreads();

  // ---------- Phase 3: edge logits (GATv2), bf16 b128 LDS reads ----------
  if (t < EPG * 4) {
    const int e = t % 56, h = t / 56;
    const int s = e / 7, k = e % 7;
    const int j = k + (k >= s ? 1 : 0);   // dst agent
    const float ea0 = s_ea[e * 3], ea1 = s_ea[e * 3 + 1], ea2 = s_ea[e * 3 + 2];
    const u16* xlp = uXL + s * XLS + h * XHS;
    const u16* xrp = uXR + j * XLS + h * XHS;
    const u16* w0p = s_w0b + h * XHS;
    const u16* w1p = s_w1b + h * XHS;
    const u16* w2p = s_w2b + h * XHS;
    const u16* bep = s_beb + h * XHS;
    const u16* atp = s_attb + h * XHS;
    float lg = 0.f;
#pragma unroll
    for (int kq = 0; kq < 8; kq++) {
      float xl8[8], xr8[8], a0[8], a1[8], a2[8], bb[8], at[8];
      b8tof(xlp + kq * 8, xl8); b8tof(xrp + kq * 8, xr8);
      b8tof(w0p + kq * 8, a0);  b8tof(w1p + kq * 8, a1);
      b8tof(w2p + kq * 8, a2);  b8tof(bep + kq * 8, bb);
      b8tof(atp + kq * 8, at);
#pragma unroll
      for (int c = 0; c < 8; c++) {
        float mv = xl8[c] + xr8[c] + ea0 * a0[c] + ea1 * a1[c] + ea2 * a2[c] + bb[c];
        mv = mv > 0.f ? mv : 0.2f * mv;
        lg += mv * at[c];
      }
    }
    s_alpha[e][h] = lg;
  }
  __syncthreads();

  // ---------- Phase 4: per-(dst,head) softmax over 7 in-edges ----------
  if (t < 32) {
    const int j = t >> 2, h = t & 3;
    float mx = -1e30f;
#pragma unroll
    for (int s = 0; s < 8; s++) {
      if (s == j) continue;
      int e = s * 7 + (j > s ? j - 1 : j);
      mx = fmaxf(mx, s_alpha[e][h]);
    }
    float sum = 0.f;
#pragma unroll
    for (int s = 0; s < 8; s++) {
      if (s == j) continue;
      int e = s * 7 + (j > s ? j - 1 : j);
      float ex = __expf(s_alpha[e][h] - mx);
      s_alpha[e][h] = ex;
      sum += ex;
    }
    float inv = 1.f / sum;
#pragma unroll
    for (int s = 0; s < 8; s++) {
      if (s == j) continue;
      int e = s * 7 + (j > s ? j - 1 : j);
      s_alpha[e][h] *= inv;
    }
  }
  __syncthreads();

  // ---------- Phase 5: aggregate, mean heads, +bias, ReLU -> h_gnn bf16 ----------
  if (t < 128) {
    const int jj = t >> 4, dq = t & 15;   // dst agent, 4-elem group
    float acc[4] = {0.f, 0.f, 0.f, 0.f};
#pragma unroll
    for (int h = 0; h < 4; h++) {
#pragma unroll
      for (int s = 0; s < 8; s++) {
        if (s == jj) continue;
        int e = s * 7 + (jj > s ? jj - 1 : jj);
        float al = s_alpha[e][h];              // broadcast
        const u16* xp = uXL + s * XLS + h * XHS + dq * 4;
        ushort4 xv = *(const ushort4*)xp;      // b64
        acc[0] += al * b2f(xv.x);
        acc[1] += al * b2f(xv.y);
        acc[2] += al * b2f(xv.z);
        acc[3] += al * b2f(xv.w);
      }
    }
    const f32x4 bg = *(const f32x4*)(bias_g + dq * 4);   // global, L2-hot
    u16 pk[4];
#pragma unroll
    for (int c = 0; c < 4; c++) {
      float v = acc[c] * 0.25f + bg[c];
      pk[c] = f2b(v > 0.f ? v : 0.f);
    }
    *(uint2*)&s_hgb[jj * ABP + dq * 4] = *(uint2*)pk;
  }
  __syncthreads();   // region switches: xl/xr dead, rz/in/hn live

  // ---------- Phase 6 (MFMA): paired gi/gh tiles; store r,z pre-summed ----------
  {
    const int arow = L & 7;
    bf16x8 ag0 = *(const bf16x8*)&s_hgb[arow * ABP + q * 8];
    bf16x8 ag1 = *(const bf16x8*)&s_hgb[arow * ABP + 32 + q * 8];
    bf16x8 ah0 = *(const bf16x8*)&s_hidb[arow * ABP + q * 8];
    bf16x8 ah1 = *(const bf16x8*)&s_hidb[arow * ABP + 32 + q * 8];
    const bf16x8* wsBv = (const bf16x8*)wsB;
#pragma unroll
    for (int i = 0; i < 3; i++) {
      const int T6 = w * 3 + i;          // 0..11
      const int Tg = 32 + T6, Th = 44 + T6;
      f32x4 acci = {0.f, 0.f, 0.f, 0.f};
      acci = __builtin_amdgcn_mfma_f32_16x16x32_bf16(ag0, wsBv[(Tg * 2 + 0) * 64 + L], acci, 0, 0, 0);
      acci = __builtin_amdgcn_mfma_f32_16x16x32_bf16(ag1, wsBv[(Tg * 2 + 1) * 64 + L], acci, 0, 0, 0);
      f32x4 acch = {0.f, 0.f, 0.f, 0.f};
      acch = __builtin_amdgcn_mfma_f32_16x16x32_bf16(ah0, wsBv[(Th * 2 + 0) * 64 + L], acch, 0, 0, 0);
      acch = __builtin_amdgcn_mfma_f32_16x16x32_bf16(ah1, wsBv[(Th * 2 + 1) * 64 + L], acch, 0, 0, 0);
      if (q < 2) {
        const int col = L & 15;
        const int gc = T6 * 16 + col;    // 0..191
        if (T6 < 8) {                    // r,z gates: store summed
#pragma unroll
          for (int r = 0; r < 4; r++)
            uF[U_RZ + (q * 4 + r) * 128 + gc] = acci[r] + acch[r] + s_bih[gc] + s_bhh[gc];
        } else {                         // n gate: keep separate
#pragma unroll
          for (int r = 0; r < 4; r++) {
            uF[U_IN + (q * 4 + r) * 64 + gc - 128] = acci[r] + s_bih[gc];
            uF[U_HN + (q * 4 + r) * 64 + gc - 128] = acch[r] + s_bhh[gc];
          }
        }
      }
    }
  }
  __syncthreads();

  // ---------- Phase 7+8 merged: GRU gates, write h, in-wave LayerNorm ----------
  {
    const float lng = ln_g[L];   // global, L2-hot
    const float lnb = ln_b[L];
#pragma unroll
    for (int rr = 0; rr < 2; rr++) {
      const int a = w + rr * 4, m = L;
      float rz_r = uF[U_RZ + a * 128 + m];
      float rz_z = uF[U_RZ + a * 128 + 64 + m];
      float inn  = uF[U_IN + a * 64 + m];
      float hn   = uF[U_HN + a * 64 + m];
      float r = 1.f / (1.f + __expf(-rz_r));
      float z = 1.f / (1.f + __expf(-rz_z));
      float xg = inn + r * hn;
      xg = fminf(fmaxf(xg, -20.f), 20.f);
      float e2 = __expf(2.f * xg);
      float n = (e2 - 1.f) / (e2 + 1.f);
      float hv = (1.f - z) * n + z * s_hid[a * MDIM + m];
      d_out[NTOT * NACT + (b * NAG + a) * MDIM + m] = hv;
      float sum = hv;
#pragma unroll
      for (int off = 1; off < 64; off <<= 1) sum += __shfl_xor(sum, off, 64);
      float mu = sum * (1.f / 64.f);
      float dv = hv - mu;
      float s2 = dv * dv;
#pragma unroll
      for (int off = 1; off < 64; off <<= 1) s2 += __shfl_xor(s2, off, 64);
      float var = s2 * (1.f / 64.f);
      uF[U_LN + a * 68 + m] = dv * rsqrtf(var + 1e-5f) * lng + lnb;
    }
  }
  __syncthreads();

  // ---------- Phase 9: q = hln @ Wq^T + bq (Wq/bq from global, L2-hot) ----------
  if (t < NAG * NACT) {
    const int a = t / NACT, o = t % NACT;
    float acc = bq[o];
    const float4* lv = (const float4*)(uF + U_LN + a * 68);
    const float4* wv = (const float4*)(Wq + o * 64);
#pragma unroll 4
    for (int kq = 0; kq < 16; kq++) {
      float4 l4 = lv[kq], w4 = wv[kq];
      acc += l4.x * w4.x + l4.y * w4.y + l4.z * w4.z + l4.w * w4.w;
    }
    d_out[(b * NAG + a) * NACT + o] = acc;
  }
}

extern "C" void kernel_launch(void* const* d_in, const int* in_sizes, int n_in,
                              void* d_out, int out_size, void* d_ws, size_t ws_size,
                              hipStream_t stream) {
  const int N  = in_sizes[0] / FIN;   // 32768
  const int Bn = N / NAG;             // 4096 episodes
  u16* wsB = (u16*)d_ws;              // 56*2*64*8 bf16 = 112 KiB

  prep_weights<<<28, 256, 0, stream>>>(
      (const float*)d_in[4],   // Wl
      (const float*)d_in[6],   // Wr
      (const float*)d_in[12],  // W_ih
      (const float*)d_in[13],  // W_hh
      wsB);

  gnn_rnn_kernel<<<Bn, 256, 0, stream>>>(
      (const float*)d_in[0], (const float*)d_in[1], (const float*)d_in[2],
      (const float*)d_in[5],   // bl
      (const float*)d_in[7],   // br
      (const float*)d_in[8],   // We
      (const float*)d_in[9],   // be
      (const float*)d_in[10],  // att
      (const float*)d_in[11],  // bias_g
      (const float*)d_in[14],  // b_ih
      (const float*)d_in[15],  // b_hh
      (const float*)d_in[16], (const float*)d_in[17],  // ln_g, ln_b
      (const float*)d_in[18], (const float*)d_in[19],  // Wq, bq
      wsB, (float*)d_out);
}

// Round 8
// 473.645 us; speedup vs baseline: 1.1197x; 1.1197x over previous
//
#include <hip/hip_runtime.h>

typedef unsigned short u16;
typedef __attribute__((ext_vector_type(8))) short bf16x8;
typedef __attribute__((ext_vector_type(4))) float f32x4;

#define NAG 8      // agents per episode
#define FIN 64
#define MDIM 64
#define NACT 10
#define EPG 56     // edges per group = 8*7
#define NTOT 32768 // B*A
#define ABP 72     // padded bf16 A-row (144 B)
#define XLS 296    // u16 stride per agent row of xl/xr (592 B; 148 words ≡ 20 mod 32)
#define XHS 72     // u16 stride per head within a row (144 B; 36 words ≡ 4 mod 32)

// union region (10368 B): phases 2-5 = bf16 xl/xr; phases 6-9 = rz/in/hn/ln (f32)
#define U_XR 2368            // u16 offset of xr (8*296)
#define U_RZ 0               // f32: rz[a][128] (r,z gate pre-sums)
#define U_IN 1024            // f32: inn[a][64]
#define U_HN 1536            // f32: hn[a][64]
#define U_LN 2048            // f32: ln[a][68]

__device__ __forceinline__ float b2f(u16 u) {
  return __uint_as_float(((unsigned int)u) << 16);
}
__device__ __forceinline__ u16 f2b(float f) {
  unsigned int x = __float_as_uint(f);
  unsigned int r = x + 0x7fffu + ((x >> 16) & 1u);   // RNE; values finite
  return (u16)(r >> 16);
}
__device__ __forceinline__ void b8tof(const u16* p, float* o) {
  bf16x8 v = *(const bf16x8*)p;
#pragma unroll
  for (int j = 0; j < 8; j++) o[j] = b2f((u16)v[j]);
}

// ---------- pre-kernel: repack Wl/Wr/W_ih/W_hh into bf16 B-fragment order ----------
__global__ __launch_bounds__(256) void prep_weights(
    const float* __restrict__ Wl, const float* __restrict__ Wr,
    const float* __restrict__ Wih, const float* __restrict__ Whh,
    u16* __restrict__ wsB)
{
  const int idx = blockIdx.x * 256 + threadIdx.x;   // 0 .. 56*2*64-1
  if (idx >= 56 * 2 * 64) return;
  const int L  = idx & 63;
  const int ks = (idx >> 6) & 1;
  const int T  = idx >> 7;
  const float* W; int row0;
  if      (T < 16) { W = Wl;  row0 = T * 16; }
  else if (T < 32) { W = Wr;  row0 = (T - 16) * 16; }
  else if (T < 44) { W = Wih; row0 = (T - 32) * 16; }
  else             { W = Whh; row0 = (T - 44) * 16; }
  const int row = row0 + (L & 15);
  const int k0  = ks * 32 + (L >> 4) * 8;
  u16 v[8];
#pragma unroll
  for (int j = 0; j < 8; j++) v[j] = f2b(W[row * 64 + k0 + j]);
  *(bf16x8*)(wsB + (size_t)idx * 8) = *(bf16x8*)v;
}

__global__ __launch_bounds__(256, 5) void gnn_rnn_kernel(
    const float* __restrict__ x, const float* __restrict__ edge_attr,
    const float* __restrict__ hidden,
    const float* __restrict__ bl, const float* __restrict__ br,
    const float* __restrict__ We, const float* __restrict__ be,
    const float* __restrict__ att, const float* __restrict__ bias_g,
    const float* __restrict__ b_ih, const float* __restrict__ b_hh,
    const float* __restrict__ ln_g, const float* __restrict__ ln_b,
    const float* __restrict__ Wq, const float* __restrict__ bq,
    const u16* __restrict__ wsB,
    float* __restrict__ d_out)
{
  __shared__ __align__(16) char uraw[10368];
  __shared__ __align__(16) u16 s_xb[NAG * ABP];     // x bf16 A-frags
  __shared__ __align__(16) u16 s_hidb[NAG * ABP];   // hidden bf16 A-frags
  __shared__ __align__(16) u16 s_hgb[NAG * ABP];    // h_gnn bf16 A-frags
  __shared__ __align__(16) float s_hid[NAG * MDIM]; // hidden f32 (gate blend)
  __shared__ float s_ea[EPG * 3];
  __shared__ __align__(16) u16 s_blb[256], s_brb[256];
  __shared__ __align__(16) u16 s_w0b[288], s_w1b[288], s_w2b[288], s_beb[288], s_attb[288];
  __shared__ float s_alpha[EPG][4];
  __shared__ float s_bih[192], s_bhh[192];

  u16*   uXL = (u16*)uraw;
  u16*   uXR = (u16*)uraw + U_XR;
  float* uF  = (float*)uraw;

  const int t = threadIdx.x;
  const int b = blockIdx.x;
  const int L = t & 63;        // lane
  const int w = t >> 6;        // wave id 0..3
  const int q = L >> 4;        // quad within wave

  // ---------- Phase 1: stage inputs + small weights ----------
  {
    const float* xb = x + b * (NAG * FIN);
    const float* hb = hidden + b * (NAG * MDIM);
#pragma unroll
    for (int i = t; i < NAG * FIN; i += 256) {
      const int a = i >> 6, m = i & 63;
      s_xb[a * ABP + m] = f2b(xb[i]);
      const float hv = hb[i];
      s_hid[a * MDIM + m] = hv;
      s_hidb[a * ABP + m] = f2b(hv);
    }
    const float* eb = edge_attr + b * (EPG * 3);
    if (t < EPG * 3) s_ea[t] = eb[t];
    s_blb[t] = f2b(bl[t]);  s_brb[t] = f2b(br[t]);
    {
      const int h = t >> 6, d = t & 63, idx = h * XHS + d;
      s_beb[idx]  = f2b(be[t]);
      s_attb[idx] = f2b(att[t]);
      s_w0b[idx]  = f2b(We[t * 3]);
      s_w1b[idx]  = f2b(We[t * 3 + 1]);
      s_w2b[idx]  = f2b(We[t * 3 + 2]);
    }
    if (t < 192)  { s_bih[t] = b_ih[t]; s_bhh[t] = b_hh[t]; }
  }
  __syncthreads();

  // ---------- Phase 2 (MFMA): xl = x@Wl^T+bl, xr = x@Wr^T+br (bf16 out) ----------
  {
    const int arow = L & 7;
    bf16x8 af0 = *(const bf16x8*)&s_xb[arow * ABP + q * 8];
    bf16x8 af1 = *(const bf16x8*)&s_xb[arow * ABP + 32 + q * 8];
    const bf16x8* wsBv = (const bf16x8*)wsB;
#pragma unroll
    for (int i = 0; i < 8; i++) {
      const int T = w * 8 + i;
      f32x4 acc = {0.f, 0.f, 0.f, 0.f};
      acc = __builtin_amdgcn_mfma_f32_16x16x32_bf16(af0, wsBv[(T * 2 + 0) * 64 + L], acc, 0, 0, 0);
      acc = __builtin_amdgcn_mfma_f32_16x16x32_bf16(af1, wsBv[(T * 2 + 1) * 64 + L], acc, 0, 0, 0);
      if (q < 2) {  // valid rows 0..7 in quads 0,1 (agent a = q*4+r)
        const int col = L & 15;
        const int Tm = T & 15;
        const int h = Tm >> 2, d = (Tm & 3) * 16 + col;
        const int gc = Tm * 16 + col;
        if (T < 16) {
          const float bias = b2f(s_blb[gc]);
#pragma unroll
          for (int r = 0; r < 4; r++)
            uXL[(q * 4 + r) * XLS + h * XHS + d] = f2b(acc[r] + bias);
        } else {
          const float bias = b2f(s_brb[gc]);
#pragma unroll
          for (int r = 0; r < 4; r++)
            uXR[(q * 4 + r) * XLS + h * XHS + d] = f2b(acc[r] + bias);
        }
      }
    }
  }
  __syncthreads();

  // ---------- Phase 3: edge logits (GATv2), bf16 b128 LDS reads ----------
  if (t < EPG * 4) {
    const int e = t % 56, h = t / 56;
    const int s = e / 7, k = e % 7;
    const int j = k + (k >= s ? 1 : 0);   // dst agent
    const float ea0 = s_ea[e * 3], ea1 = s_ea[e * 3 + 1], ea2 = s_ea[e * 3 + 2];
    const u16* xlp = uXL + s * XLS + h * XHS;
    const u16* xrp = uXR + j * XLS + h * XHS;
    const u16* w0p = s_w0b + h * XHS;
    const u16* w1p = s_w1b + h * XHS;
    const u16* w2p = s_w2b + h * XHS;
    const u16* bep = s_beb + h * XHS;
    const u16* atp = s_attb + h * XHS;
    float lg = 0.f;
#pragma unroll
    for (int kq = 0; kq < 8; kq++) {
      float xl8[8], xr8[8], a0[8], a1[8], a2[8], bb[8], at[8];
      b8tof(xlp + kq * 8, xl8); b8tof(xrp + kq * 8, xr8);
      b8tof(w0p + kq * 8, a0);  b8tof(w1p + kq * 8, a1);
      b8tof(w2p + kq * 8, a2);  b8tof(bep + kq * 8, bb);
      b8tof(atp + kq * 8, at);
#pragma unroll
      for (int c = 0; c < 8; c++) {
        float mv = xl8[c] + xr8[c] + ea0 * a0[c] + ea1 * a1[c] + ea2 * a2[c] + bb[c];
        mv = mv > 0.f ? mv : 0.2f * mv;
        lg += mv * at[c];
      }
    }
    s_alpha[e][h] = lg;
  }
  __syncthreads();

  // ---------- Phase 4: per-(dst,head) softmax over 7 in-edges ----------
  if (t < 32) {
    const int j = t >> 2, h = t & 3;
    float mx = -1e30f;
#pragma unroll
    for (int s = 0; s < 8; s++) {
      if (s == j) continue;
      int e = s * 7 + (j > s ? j - 1 : j);
      mx = fmaxf(mx, s_alpha[e][h]);
    }
    float sum = 0.f;
#pragma unroll
    for (int s = 0; s < 8; s++) {
      if (s == j) continue;
      int e = s * 7 + (j > s ? j - 1 : j);
      float ex = __expf(s_alpha[e][h] - mx);
      s_alpha[e][h] = ex;
      sum += ex;
    }
    float inv = 1.f / sum;
#pragma unroll
    for (int s = 0; s < 8; s++) {
      if (s == j) continue;
      int e = s * 7 + (j > s ? j - 1 : j);
      s_alpha[e][h] *= inv;
    }
  }
  __syncthreads();

  // ---------- Phase 5: aggregate, mean heads, +bias, ReLU -> h_gnn bf16 ----------
  if (t < 128) {
    const int jj = t >> 4, dq = t & 15;   // dst agent, 4-elem group
    float acc[4] = {0.f, 0.f, 0.f, 0.f};
#pragma unroll
    for (int h = 0; h < 4; h++) {
#pragma unroll
      for (int s = 0; s < 8; s++) {
        if (s == jj) continue;
        int e = s * 7 + (jj > s ? jj - 1 : jj);
        float al = s_alpha[e][h];              // broadcast
        const u16* xp = uXL + s * XLS + h * XHS + dq * 4;
        ushort4 xv = *(const ushort4*)xp;      // b64
        acc[0] += al * b2f(xv.x);
        acc[1] += al * b2f(xv.y);
        acc[2] += al * b2f(xv.z);
        acc[3] += al * b2f(xv.w);
      }
    }
    const f32x4 bg = *(const f32x4*)(bias_g + dq * 4);   // global, L2-hot
    u16 pk[4];
#pragma unroll
    for (int c = 0; c < 4; c++) {
      float v = acc[c] * 0.25f + bg[c];
      pk[c] = f2b(v > 0.f ? v : 0.f);
    }
    *(uint2*)&s_hgb[jj * ABP + dq * 4] = *(uint2*)pk;
  }
  __syncthreads();   // region switches: xl/xr dead, rz/in/hn live

  // ---------- Phase 6 (MFMA): paired gi/gh tiles; store r,z pre-summed ----------
  {
    const int arow = L & 7;
    bf16x8 ag0 = *(const bf16x8*)&s_hgb[arow * ABP + q * 8];
    bf16x8 ag1 = *(const bf16x8*)&s_hgb[arow * ABP + 32 + q * 8];
    bf16x8 ah0 = *(const bf16x8*)&s_hidb[arow * ABP + q * 8];
    bf16x8 ah1 = *(const bf16x8*)&s_hidb[arow * ABP + 32 + q * 8];
    const bf16x8* wsBv = (const bf16x8*)wsB;
#pragma unroll
    for (int i = 0; i < 3; i++) {
      const int T6 = w * 3 + i;          // 0..11
      const int Tg = 32 + T6, Th = 44 + T6;
      f32x4 acci = {0.f, 0.f, 0.f, 0.f};
      acci = __builtin_amdgcn_mfma_f32_16x16x32_bf16(ag0, wsBv[(Tg * 2 + 0) * 64 + L], acci, 0, 0, 0);
      acci = __builtin_amdgcn_mfma_f32_16x16x32_bf16(ag1, wsBv[(Tg * 2 + 1) * 64 + L], acci, 0, 0, 0);
      f32x4 acch = {0.f, 0.f, 0.f, 0.f};
      acch = __builtin_amdgcn_mfma_f32_16x16x32_bf16(ah0, wsBv[(Th * 2 + 0) * 64 + L], acch, 0, 0, 0);
      acch = __builtin_amdgcn_mfma_f32_16x16x32_bf16(ah1, wsBv[(Th * 2 + 1) * 64 + L], acch, 0, 0, 0);
      if (q < 2) {
        const int col = L & 15;
        const int gc = T6 * 16 + col;    // 0..191
        if (T6 < 8) {                    // r,z gates: store summed
#pragma unroll
          for (int r = 0; r < 4; r++)
            uF[U_RZ + (q * 4 + r) * 128 + gc] = acci[r] + acch[r] + s_bih[gc] + s_bhh[gc];
        } else {                         // n gate: keep separate
#pragma unroll
          for (int r = 0; r < 4; r++) {
            uF[U_IN + (q * 4 + r) * 64 + gc - 128] = acci[r] + s_bih[gc];
            uF[U_HN + (q * 4 + r) * 64 + gc - 128] = acch[r] + s_bhh[gc];
          }
        }
      }
    }
  }
  __syncthreads();

  // ---------- Phase 7+8 merged: GRU gates, write h, in-wave LayerNorm ----------
  {
    const float lng = ln_g[L];   // global, L2-hot
    const float lnb = ln_b[L];
#pragma unroll
    for (int rr = 0; rr < 2; rr++) {
      const int a = w + rr * 4, m = L;
      float rz_r = uF[U_RZ + a * 128 + m];
      float rz_z = uF[U_RZ + a * 128 + 64 + m];
      float inn  = uF[U_IN + a * 64 + m];
      float hn   = uF[U_HN + a * 64 + m];
      float r = 1.f / (1.f + __expf(-rz_r));
      float z = 1.f / (1.f + __expf(-rz_z));
      float xg = inn + r * hn;
      xg = fminf(fmaxf(xg, -20.f), 20.f);
      float e2 = __expf(2.f * xg);
      float n = (e2 - 1.f) / (e2 + 1.f);
      float hv = (1.f - z) * n + z * s_hid[a * MDIM + m];
      d_out[NTOT * NACT + (b * NAG + a) * MDIM + m] = hv;
      float sum = hv;
#pragma unroll
      for (int off = 1; off < 64; off <<= 1) sum += __shfl_xor(sum, off, 64);
      float mu = sum * (1.f / 64.f);
      float dv = hv - mu;
      float s2 = dv * dv;
#pragma unroll
      for (int off = 1; off < 64; off <<= 1) s2 += __shfl_xor(s2, off, 64);
      float var = s2 * (1.f / 64.f);
      uF[U_LN + a * 68 + m] = dv * rsqrtf(var + 1e-5f) * lng + lnb;
    }
  }
  __syncthreads();

  // ---------- Phase 9: q = hln @ Wq^T + bq (Wq/bq from global, L2-hot) ----------
  if (t < NAG * NACT) {
    const int a = t / NACT, o = t % NACT;
    float acc = bq[o];
    const float4* lv = (const float4*)(uF + U_LN + a * 68);
    const float4* wv = (const float4*)(Wq + o * 64);
#pragma unroll 4
    for (int kq = 0; kq < 16; kq++) {
      float4 l4 = lv[kq], w4 = wv[kq];
      acc += l4.x * w4.x + l4.y * w4.y + l4.z * w4.z + l4.w * w4.w;
    }
    d_out[(b * NAG + a) * NACT + o] = acc;
  }
}

extern "C" void kernel_launch(void* const* d_in, const int* in_sizes, int n_in,
                              void* d_out, int out_size, void* d_ws, size_t ws_size,
                              hipStream_t stream) {
  const int N  = in_sizes[0] / FIN;   // 32768
  const int Bn = N / NAG;             // 4096 episodes
  u16* wsB = (u16*)d_ws;              // 56*2*64*8 bf16 = 112 KiB

  prep_weights<<<28, 256, 0, stream>>>(
      (const float*)d_in[4],   // Wl
      (const float*)d_in[6],   // Wr
      (const float*)d_in[12],  // W_ih
      (const float*)d_in[13],  // W_hh
      wsB);

  gnn_rnn_kernel<<<Bn, 256, 0, stream>>>(
      (const float*)d_in[0], (const float*)d_in[1], (const float*)d_in[2],
      (const float*)d_in[5],   // bl
      (const float*)d_in[7],   // br
      (const float*)d_in[8],   // We
      (const float*)d_in[9],   // be
      (const float*)d_in[10],  // att
      (const float*)d_in[11],  // bias_g
      (const float*)d_in[14],  // b_ih
      (const float*)d_in[15],  // b_hh
      (const float*)d_in[16], (const float*)d_in[17],  // ln_g, ln_b
      (const float*)d_in[18], (const float*)d_in[19],  // Wq, bq
      wsB, (float*)d_out);
}

// Round 9
// 161.416 us; speedup vs baseline: 3.2854x; 2.9343x over previous
//
#include <hip/hip_runtime.h>

typedef unsigned short u16;
typedef __attribute__((ext_vector_type(8))) short bf16x8;
typedef __attribute__((ext_vector_type(4))) float f32x4;

#define NAG 8      // agents per episode
#define FIN 64
#define MDIM 64
#define NACT 10
#define EPG 56     // edges per group = 8*7
#define NTOT 32768 // B*A
#define ABP 72     // padded bf16 A-row (144 B)
#define XLS 296    // u16 stride per agent row of xl/xr (592 B; 148 words ≡ 20 mod 32)
#define XHS 72     // u16 stride per head within a row (144 B; 36 words ≡ 4 mod 32)

// union region (10368 B): phases 2-5 = bf16 xl/xr; phases 6-9 = rz/in/hn/ln (f32)
#define U_XR 2368            // u16 offset of xr (8*296)
#define U_RZ 0               // f32: rz[a][128] (r,z gate pre-sums)
#define U_IN 1024            // f32: inn[a][64]
#define U_HN 1536            // f32: hn[a][64]
#define U_LN 2048            // f32: ln[a][68]

__device__ __forceinline__ float b2f(u16 u) {
  return __uint_as_float(((unsigned int)u) << 16);
}
__device__ __forceinline__ u16 f2b(float f) {
  unsigned int x = __float_as_uint(f);
  unsigned int r = x + 0x7fffu + ((x >> 16) & 1u);   // RNE; values finite
  return (u16)(r >> 16);
}

// ---------- pre-kernel: repack Wl/Wr/W_ih/W_hh into bf16 B-fragment order ----------
__global__ __launch_bounds__(256) void prep_weights(
    const float* __restrict__ Wl, const float* __restrict__ Wr,
    const float* __restrict__ Wih, const float* __restrict__ Whh,
    u16* __restrict__ wsB)
{
  const int idx = blockIdx.x * 256 + threadIdx.x;   // 0 .. 56*2*64-1
  if (idx >= 56 * 2 * 64) return;
  const int L  = idx & 63;
  const int ks = (idx >> 6) & 1;
  const int T  = idx >> 7;
  const float* W; int row0;
  if      (T < 16) { W = Wl;  row0 = T * 16; }
  else if (T < 32) { W = Wr;  row0 = (T - 16) * 16; }
  else if (T < 44) { W = Wih; row0 = (T - 32) * 16; }
  else             { W = Whh; row0 = (T - 44) * 16; }
  const int row = row0 + (L & 15);
  const int k0  = ks * 32 + (L >> 4) * 8;
  u16 v[8];
#pragma unroll
  for (int j = 0; j < 8; j++) v[j] = f2b(W[row * 64 + k0 + j]);
  *(bf16x8*)(wsB + (size_t)idx * 8) = *(bf16x8*)v;
}

__global__ __launch_bounds__(256, 4) void gnn_rnn_kernel(
    const float* __restrict__ x, const float* __restrict__ edge_attr,
    const float* __restrict__ hidden,
    const float* __restrict__ bl, const float* __restrict__ br,
    const float* __restrict__ We, const float* __restrict__ be,
    const float* __restrict__ att, const float* __restrict__ bias_g,
    const float* __restrict__ b_ih, const float* __restrict__ b_hh,
    const float* __restrict__ ln_g, const float* __restrict__ ln_b,
    const float* __restrict__ Wq, const float* __restrict__ bq,
    const u16* __restrict__ wsB,
    float* __restrict__ d_out)
{
  __shared__ __align__(16) char uraw[10368];
  __shared__ __align__(16) u16 s_xb[NAG * ABP];     // x bf16 A-frags
  __shared__ __align__(16) u16 s_hidb[NAG * ABP];   // hidden bf16 A-frags
  __shared__ __align__(16) u16 s_hgb[NAG * ABP];    // h_gnn bf16 A-frags
  __shared__ __align__(16) float s_hid[NAG * MDIM]; // hidden f32 (gate blend)
  __shared__ float s_ea[EPG * 3];
  __shared__ __align__(16) u16 s_blb[256], s_brb[256];
  __shared__ __align__(16) u16 s_w0b[288], s_w1b[288], s_w2b[288], s_beb[288], s_attb[288];
  __shared__ float s_alpha[EPG][4];
  __shared__ float s_bih[192], s_bhh[192];

  u16*   uXL = (u16*)uraw;
  u16*   uXR = (u16*)uraw + U_XR;
  float* uF  = (float*)uraw;

  const int t = threadIdx.x;
  const int b = blockIdx.x;
  const int L = t & 63;        // lane
  const int w = t >> 6;        // wave id 0..3
  const int q = L >> 4;        // quad within wave

  // ---------- Phase 1: stage inputs + small weights ----------
  {
    const float* xb = x + b * (NAG * FIN);
    const float* hb = hidden + b * (NAG * MDIM);
#pragma unroll
    for (int i = t; i < NAG * FIN; i += 256) {
      const int a = i >> 6, m = i & 63;
      s_xb[a * ABP + m] = f2b(xb[i]);
      const float hv = hb[i];
      s_hid[a * MDIM + m] = hv;
      s_hidb[a * ABP + m] = f2b(hv);
    }
    const float* eb = edge_attr + b * (EPG * 3);
    if (t < EPG * 3) s_ea[t] = eb[t];
    s_blb[t] = f2b(bl[t]);  s_brb[t] = f2b(br[t]);
    {
      const int h = t >> 6, d = t & 63, idx = h * XHS + d;
      s_beb[idx]  = f2b(be[t]);
      s_attb[idx] = f2b(att[t]);
      s_w0b[idx]  = f2b(We[t * 3]);
      s_w1b[idx]  = f2b(We[t * 3 + 1]);
      s_w2b[idx]  = f2b(We[t * 3 + 2]);
    }
    if (t < 192)  { s_bih[t] = b_ih[t]; s_bhh[t] = b_hh[t]; }
  }
  __syncthreads();

  // ---------- Phase 2 (MFMA): xl = x@Wl^T+bl, xr = x@Wr^T+br (bf16 out) ----------
  {
    const int arow = L & 7;
    bf16x8 af0 = *(const bf16x8*)&s_xb[arow * ABP + q * 8];
    bf16x8 af1 = *(const bf16x8*)&s_xb[arow * ABP + 32 + q * 8];
    const bf16x8* wsBv = (const bf16x8*)wsB;
#pragma unroll 4
    for (int i = 0; i < 8; i++) {
      const int T = w * 8 + i;
      f32x4 acc = {0.f, 0.f, 0.f, 0.f};
      acc = __builtin_amdgcn_mfma_f32_16x16x32_bf16(af0, wsBv[(T * 2 + 0) * 64 + L], acc, 0, 0, 0);
      acc = __builtin_amdgcn_mfma_f32_16x16x32_bf16(af1, wsBv[(T * 2 + 1) * 64 + L], acc, 0, 0, 0);
      if (q < 2) {  // valid rows 0..7 in quads 0,1 (agent a = q*4+r)
        const int col = L & 15;
        const int Tm = T & 15;
        const int h = Tm >> 2, d = (Tm & 3) * 16 + col;
        const int gc = Tm * 16 + col;
        if (T < 16) {
          const float bias = b2f(s_blb[gc]);
#pragma unroll
          for (int r = 0; r < 4; r++)
            uXL[(q * 4 + r) * XLS + h * XHS + d] = f2b(acc[r] + bias);
        } else {
          const float bias = b2f(s_brb[gc]);
#pragma unroll
          for (int r = 0; r < 4; r++)
            uXR[(q * 4 + r) * XLS + h * XHS + d] = f2b(acc[r] + bias);
        }
      }
    }
  }
  __syncthreads();

  // ---------- Phase 3: edge logits (GATv2), bf16 b128 LDS reads, low reg pressure ----------
  if (t < EPG * 4) {
    const int e = t % 56, h = t / 56;
    const int s = e / 7, k = e % 7;
    const int j = k + (k >= s ? 1 : 0);   // dst agent
    const float ea0 = s_ea[e * 3], ea1 = s_ea[e * 3 + 1], ea2 = s_ea[e * 3 + 2];
    const u16* xlp = uXL + s * XLS + h * XHS;
    const u16* xrp = uXR + j * XLS + h * XHS;
    const u16* w0p = s_w0b + h * XHS;
    const u16* w1p = s_w1b + h * XHS;
    const u16* w2p = s_w2b + h * XHS;
    const u16* bep = s_beb + h * XHS;
    const u16* atp = s_attb + h * XHS;
    float lg = 0.f;
#pragma unroll 2
    for (int kq = 0; kq < 8; kq++) {
      bf16x8 vxl = *(const bf16x8*)(xlp + kq * 8);
      bf16x8 vxr = *(const bf16x8*)(xrp + kq * 8);
      bf16x8 v0  = *(const bf16x8*)(w0p + kq * 8);
      bf16x8 v1  = *(const bf16x8*)(w1p + kq * 8);
      bf16x8 v2  = *(const bf16x8*)(w2p + kq * 8);
      bf16x8 vb  = *(const bf16x8*)(bep + kq * 8);
      bf16x8 va  = *(const bf16x8*)(atp + kq * 8);
#pragma unroll
      for (int c = 0; c < 8; c++) {
        float mv = b2f((u16)vxl[c]) + b2f((u16)vxr[c])
                 + ea0 * b2f((u16)v0[c]) + ea1 * b2f((u16)v1[c])
                 + ea2 * b2f((u16)v2[c]) + b2f((u16)vb[c]);
        mv = mv > 0.f ? mv : 0.2f * mv;
        lg += mv * b2f((u16)va[c]);
      }
    }
    s_alpha[e][h] = lg;
  }
  __syncthreads();

  // ---------- Phase 4: per-(dst,head) softmax over 7 in-edges ----------
  if (t < 32) {
    const int j = t >> 2, h = t & 3;
    float mx = -1e30f;
#pragma unroll
    for (int s = 0; s < 8; s++) {
      if (s == j) continue;
      int e = s * 7 + (j > s ? j - 1 : j);
      mx = fmaxf(mx, s_alpha[e][h]);
    }
    float sum = 0.f;
#pragma unroll
    for (int s = 0; s < 8; s++) {
      if (s == j) continue;
      int e = s * 7 + (j > s ? j - 1 : j);
      float ex = __expf(s_alpha[e][h] - mx);
      s_alpha[e][h] = ex;
      sum += ex;
    }
    float inv = 1.f / sum;
#pragma unroll
    for (int s = 0; s < 8; s++) {
      if (s == j) continue;
      int e = s * 7 + (j > s ? j - 1 : j);
      s_alpha[e][h] *= inv;
    }
  }
  __syncthreads();

  // ---------- Phase 5: aggregate, mean heads, +bias, ReLU -> h_gnn bf16 ----------
  if (t < 128) {
    const int jj = t >> 4, dq = t & 15;   // dst agent, 4-elem group
    float acc[4] = {0.f, 0.f, 0.f, 0.f};
#pragma unroll 2
    for (int h = 0; h < 4; h++) {
#pragma unroll
      for (int s = 0; s < 8; s++) {
        if (s == jj) continue;
        int e = s * 7 + (jj > s ? jj - 1 : jj);
        float al = s_alpha[e][h];              // broadcast
        const u16* xp = uXL + s * XLS + h * XHS + dq * 4;
        ushort4 xv = *(const ushort4*)xp;      // b64
        acc[0] += al * b2f(xv.x);
        acc[1] += al * b2f(xv.y);
        acc[2] += al * b2f(xv.z);
        acc[3] += al * b2f(xv.w);
      }
    }
    const f32x4 bg = *(const f32x4*)(bias_g + dq * 4);   // global, L2-hot
    u16 pk[4];
#pragma unroll
    for (int c = 0; c < 4; c++) {
      float v = acc[c] * 0.25f + bg[c];
      pk[c] = f2b(v > 0.f ? v : 0.f);
    }
    *(uint2*)&s_hgb[jj * ABP + dq * 4] = *(uint2*)pk;
  }
  __syncthreads();   // region switches: xl/xr dead, rz/in/hn live

  // ---------- Phase 6 (MFMA): paired gi/gh tiles; store r,z pre-summed ----------
  {
    const int arow = L & 7;
    bf16x8 ag0 = *(const bf16x8*)&s_hgb[arow * ABP + q * 8];
    bf16x8 ag1 = *(const bf16x8*)&s_hgb[arow * ABP + 32 + q * 8];
    bf16x8 ah0 = *(const bf16x8*)&s_hidb[arow * ABP + q * 8];
    bf16x8 ah1 = *(const bf16x8*)&s_hidb[arow * ABP + 32 + q * 8];
    const bf16x8* wsBv = (const bf16x8*)wsB;
#pragma unroll
    for (int i = 0; i < 3; i++) {
      const int T6 = w * 3 + i;          // 0..11
      const int Tg = 32 + T6, Th = 44 + T6;
      f32x4 acci = {0.f, 0.f, 0.f, 0.f};
      acci = __builtin_amdgcn_mfma_f32_16x16x32_bf16(ag0, wsBv[(Tg * 2 + 0) * 64 + L], acci, 0, 0, 0);
      acci = __builtin_amdgcn_mfma_f32_16x16x32_bf16(ag1, wsBv[(Tg * 2 + 1) * 64 + L], acci, 0, 0, 0);
      f32x4 acch = {0.f, 0.f, 0.f, 0.f};
      acch = __builtin_amdgcn_mfma_f32_16x16x32_bf16(ah0, wsBv[(Th * 2 + 0) * 64 + L], acch, 0, 0, 0);
      acch = __builtin_amdgcn_mfma_f32_16x16x32_bf16(ah1, wsBv[(Th * 2 + 1) * 64 + L], acch, 0, 0, 0);
      if (q < 2) {
        const int col = L & 15;
        const int gc = T6 * 16 + col;    // 0..191
        if (T6 < 8) {                    // r,z gates: store summed
#pragma unroll
          for (int r = 0; r < 4; r++)
            uF[U_RZ + (q * 4 + r) * 128 + gc] = acci[r] + acch[r] + s_bih[gc] + s_bhh[gc];
        } else {                         // n gate: keep separate
#pragma unroll
          for (int r = 0; r < 4; r++) {
            uF[U_IN + (q * 4 + r) * 64 + gc - 128] = acci[r] + s_bih[gc];
            uF[U_HN + (q * 4 + r) * 64 + gc - 128] = acch[r] + s_bhh[gc];
          }
        }
      }
    }
  }
  __syncthreads();

  // ---------- Phase 7+8 merged: GRU gates, write h, in-wave LayerNorm ----------
  {
    const float lng = ln_g[L];   // global, L2-hot
    const float lnb = ln_b[L];
#pragma unroll
    for (int rr = 0; rr < 2; rr++) {
      const int a = w + rr * 4, m = L;
      float rz_r = uF[U_RZ + a * 128 + m];
      float rz_z = uF[U_RZ + a * 128 + 64 + m];
      float inn  = uF[U_IN + a * 64 + m];
      float hn   = uF[U_HN + a * 64 + m];
      float r = 1.f / (1.f + __expf(-rz_r));
      float z = 1.f / (1.f + __expf(-rz_z));
      float xg = inn + r * hn;
      xg = fminf(fmaxf(xg, -20.f), 20.f);
      float e2 = __expf(2.f * xg);
      float n = (e2 - 1.f) / (e2 + 1.f);
      float hv = (1.f - z) * n + z * s_hid[a * MDIM + m];
      d_out[NTOT * NACT + (b * NAG + a) * MDIM + m] = hv;
      float sum = hv;
#pragma unroll
      for (int off = 1; off < 64; off <<= 1) sum += __shfl_xor(sum, off, 64);
      float mu = sum * (1.f / 64.f);
      float dv = hv - mu;
      float s2 = dv * dv;
#pragma unroll
      for (int off = 1; off < 64; off <<= 1) s2 += __shfl_xor(s2, off, 64);
      float var = s2 * (1.f / 64.f);
      uF[U_LN + a * 68 + m] = dv * rsqrtf(var + 1e-5f) * lng + lnb;
    }
  }
  __syncthreads();

  // ---------- Phase 9: q = hln @ Wq^T + bq (Wq/bq from global, L2-hot) ----------
  if (t < NAG * NACT) {
    const int a = t / NACT, o = t % NACT;
    float acc = bq[o];
    const float4* lv = (const float4*)(uF + U_LN + a * 68);
    const float4* wv = (const float4*)(Wq + o * 64);
#pragma unroll 4
    for (int kq = 0; kq < 16; kq++) {
      float4 l4 = lv[kq], w4 = wv[kq];
      acc += l4.x * w4.x + l4.y * w4.y + l4.z * w4.z + l4.w * w4.w;
    }
    d_out[(b * NAG + a) * NACT + o] = acc;
  }
}

extern "C" void kernel_launch(void* const* d_in, const int* in_sizes, int n_in,
                              void* d_out, int out_size, void* d_ws, size_t ws_size,
                              hipStream_t stream) {
  const int N  = in_sizes[0] / FIN;   // 32768
  const int Bn = N / NAG;             // 4096 episodes
  u16* wsB = (u16*)d_ws;              // 56*2*64*8 bf16 = 112 KiB

  prep_weights<<<28, 256, 0, stream>>>(
      (const float*)d_in[4],   // Wl
      (const float*)d_in[6],   // Wr
      (const float*)d_in[12],  // W_ih
      (const float*)d_in[13],  // W_hh
      wsB);

  gnn_rnn_kernel<<<Bn, 256, 0, stream>>>(
      (const float*)d_in[0], (const float*)d_in[1], (const float*)d_in[2],
      (const float*)d_in[5],   // bl
      (const float*)d_in[7],   // br
      (const float*)d_in[8],   // We
      (const float*)d_in[9],   // be
      (const float*)d_in[10],  // att
      (const float*)d_in[11],  // bias_g
      (const float*)d_in[14],  // b_ih
      (const float*)d_in[15],  // b_hh
      (const float*)d_in[16], (const float*)d_in[17],  // ln_g, ln_b
      (const float*)d_in[18], (const float*)d_in[19],  // Wq, bq
      wsB, (float*)d_out);
}

// Round 10
// 157.272 us; speedup vs baseline: 3.3720x; 1.0264x over previous
//
#include <hip/hip_runtime.h>

typedef unsigned short u16;
typedef __attribute__((ext_vector_type(8))) short bf16x8;
typedef __attribute__((ext_vector_type(4))) float f32x4;

#define NAG 8      // agents per episode
#define NAGB 16    // agents per block (2 episodes)
#define FIN 64
#define MDIM 64
#define NACT 10
#define EPG 56     // edges per episode = 8*7
#define NTOT 32768 // B*A
#define ABP 72     // padded bf16 A-row (144 B)
#define XLS 296    // u16 stride per agent row of xl/xr (148 words ≡ 20 mod 32)
#define XHS 72     // u16 stride per head within a row (36 words ≡ 4 mod 32)

// union region (20736 B): phases 2-5 = bf16 xl/xr (16 rows); phases 6-9 = f32 rz/in/hn/ln
#define U_XR 4736            // u16 offset of xr (16*296)
#define U_RZ 0               // f32: rz[a][128]
#define U_IN 2048            // f32: inn[a][64]
#define U_HN 3072            // f32: hn[a][64]
#define U_LN 4096            // f32: ln[a][68]

__device__ __forceinline__ float b2f(u16 u) {
  return __uint_as_float(((unsigned int)u) << 16);
}
__device__ __forceinline__ u16 f2b(float f) {
  unsigned int x = __float_as_uint(f);
  unsigned int r = x + 0x7fffu + ((x >> 16) & 1u);   // RNE; values finite
  return (u16)(r >> 16);
}

// ---------- pre-kernel: repack Wl/Wr/W_ih/W_hh into bf16 B-fragment order ----------
__global__ __launch_bounds__(256) void prep_weights(
    const float* __restrict__ Wl, const float* __restrict__ Wr,
    const float* __restrict__ Wih, const float* __restrict__ Whh,
    u16* __restrict__ wsB)
{
  const int idx = blockIdx.x * 256 + threadIdx.x;   // 0 .. 56*2*64-1
  if (idx >= 56 * 2 * 64) return;
  const int L  = idx & 63;
  const int ks = (idx >> 6) & 1;
  const int T  = idx >> 7;
  const float* W; int row0;
  if      (T < 16) { W = Wl;  row0 = T * 16; }
  else if (T < 32) { W = Wr;  row0 = (T - 16) * 16; }
  else if (T < 44) { W = Wih; row0 = (T - 32) * 16; }
  else             { W = Whh; row0 = (T - 44) * 16; }
  const int row = row0 + (L & 15);
  const int k0  = ks * 32 + (L >> 4) * 8;
  u16 v[8];
#pragma unroll
  for (int j = 0; j < 8; j++) v[j] = f2b(W[row * 64 + k0 + j]);
  *(bf16x8*)(wsB + (size_t)idx * 8) = *(bf16x8*)v;
}

__global__ __launch_bounds__(256, 4) void gnn_rnn_kernel(
    const float* __restrict__ x, const float* __restrict__ edge_attr,
    const float* __restrict__ hidden,
    const float* __restrict__ bl, const float* __restrict__ br,
    const float* __restrict__ We, const float* __restrict__ be,
    const float* __restrict__ att, const float* __restrict__ bias_g,
    const float* __restrict__ b_ih, const float* __restrict__ b_hh,
    const float* __restrict__ ln_g, const float* __restrict__ ln_b,
    const float* __restrict__ Wq, const float* __restrict__ bq,
    const u16* __restrict__ wsB,
    float* __restrict__ d_out)
{
  __shared__ __align__(16) char uraw[20736];
  __shared__ __align__(16) u16 s_xb[NAGB * ABP];    // x bf16 A-frags (16 agents)
  __shared__ __align__(16) u16 s_hidb[NAGB * ABP];  // hidden bf16 A-frags
  __shared__ __align__(16) u16 s_hgb[NAGB * ABP];   // h_gnn bf16 A-frags
  __shared__ float s_ea[2 * EPG * 3];
  __shared__ __align__(16) u16 s_blb[256], s_brb[256];
  __shared__ __align__(16) u16 s_w0b[288], s_w1b[288], s_w2b[288], s_beb[288], s_attb[288];
  __shared__ float s_alpha[2 * EPG][4];
  __shared__ float s_bih[192], s_bhh[192];

  u16*   uXL = (u16*)uraw;
  u16*   uXR = (u16*)uraw + U_XR;
  float* uF  = (float*)uraw;

  const int t = threadIdx.x;
  const int b = blockIdx.x;    // 2-episode group
  const int L = t & 63;        // lane
  const int w = t >> 6;        // wave id 0..3
  const int q = L >> 4;        // quad within wave

  // ---------- Phase 1: stage inputs + small weights ----------
  {
    const float* xb = x + b * (NAGB * FIN);
    const float* hb = hidden + b * (NAGB * MDIM);
#pragma unroll
    for (int i = t; i < NAGB * FIN; i += 256) {
      const int a = i >> 6, m = i & 63;
      s_xb[a * ABP + m] = f2b(xb[i]);
      s_hidb[a * ABP + m] = f2b(hb[i]);
    }
    const float* eb = edge_attr + b * (2 * EPG * 3);
    for (int i = t; i < 2 * EPG * 3; i += 256) s_ea[i] = eb[i];
    s_blb[t] = f2b(bl[t]);  s_brb[t] = f2b(br[t]);
    {
      const int h = t >> 6, d = t & 63, idx = h * XHS + d;
      s_beb[idx]  = f2b(be[t]);
      s_attb[idx] = f2b(att[t]);
      s_w0b[idx]  = f2b(We[t * 3]);
      s_w1b[idx]  = f2b(We[t * 3 + 1]);
      s_w2b[idx]  = f2b(We[t * 3 + 2]);
    }
    if (t < 192)  { s_bih[t] = b_ih[t]; s_bhh[t] = b_hh[t]; }
  }
  __syncthreads();

  // ---------- Phase 2 (MFMA): xl/xr for 16 agents (all tile rows valid) ----------
  {
    const int arow = L & 15;
    bf16x8 af0 = *(const bf16x8*)&s_xb[arow * ABP + q * 8];
    bf16x8 af1 = *(const bf16x8*)&s_xb[arow * ABP + 32 + q * 8];
    const bf16x8* wsBv = (const bf16x8*)wsB;
#pragma unroll 4
    for (int i = 0; i < 8; i++) {
      const int T = w * 8 + i;
      f32x4 acc = {0.f, 0.f, 0.f, 0.f};
      acc = __builtin_amdgcn_mfma_f32_16x16x32_bf16(af0, wsBv[(T * 2 + 0) * 64 + L], acc, 0, 0, 0);
      acc = __builtin_amdgcn_mfma_f32_16x16x32_bf16(af1, wsBv[(T * 2 + 1) * 64 + L], acc, 0, 0, 0);
      const int col = L & 15;
      const int Tm = T & 15;
      const int h = Tm >> 2, d = (Tm & 3) * 16 + col;
      const int gc = Tm * 16 + col;
      if (T < 16) {
        const float bias = b2f(s_blb[gc]);
#pragma unroll
        for (int r = 0; r < 4; r++)
          uXL[(q * 4 + r) * XLS + h * XHS + d] = f2b(acc[r] + bias);
      } else {
        const float bias = b2f(s_brb[gc]);
#pragma unroll
        for (int r = 0; r < 4; r++)
          uXR[(q * 4 + r) * XLS + h * XHS + d] = f2b(acc[r] + bias);
      }
    }
  }
  __syncthreads();

  // ---------- Phase 3: edge logits, both episodes ----------
  for (int ep = 0; ep < 2; ep++) {
    if (t < EPG * 4) {
      const int e = t % 56, h = t / 56;
      const int s = e / 7, k = e % 7;
      const int j = k + (k >= s ? 1 : 0);   // dst agent
      const int eg = ep * EPG + e;
      const float ea0 = s_ea[eg * 3], ea1 = s_ea[eg * 3 + 1], ea2 = s_ea[eg * 3 + 2];
      const u16* xlp = uXL + (ep * 8 + s) * XLS + h * XHS;
      const u16* xrp = uXR + (ep * 8 + j) * XLS + h * XHS;
      const u16* w0p = s_w0b + h * XHS;
      const u16* w1p = s_w1b + h * XHS;
      const u16* w2p = s_w2b + h * XHS;
      const u16* bep = s_beb + h * XHS;
      const u16* atp = s_attb + h * XHS;
      float lg = 0.f;
#pragma unroll 2
      for (int kq = 0; kq < 8; kq++) {
        bf16x8 vxl = *(const bf16x8*)(xlp + kq * 8);
        bf16x8 vxr = *(const bf16x8*)(xrp + kq * 8);
        bf16x8 v0  = *(const bf16x8*)(w0p + kq * 8);
        bf16x8 v1  = *(const bf16x8*)(w1p + kq * 8);
        bf16x8 v2  = *(const bf16x8*)(w2p + kq * 8);
        bf16x8 vb  = *(const bf16x8*)(bep + kq * 8);
        bf16x8 va  = *(const bf16x8*)(atp + kq * 8);
#pragma unroll
        for (int c = 0; c < 8; c++) {
          float mv = b2f((u16)vxl[c]) + b2f((u16)vxr[c])
                   + ea0 * b2f((u16)v0[c]) + ea1 * b2f((u16)v1[c])
                   + ea2 * b2f((u16)v2[c]) + b2f((u16)vb[c]);
          mv = mv > 0.f ? mv : 0.2f * mv;
          lg += mv * b2f((u16)va[c]);
        }
      }
      s_alpha[eg][h] = lg;
    }
  }
  __syncthreads();

  // ---------- Phase 4: softmax per (episode, dst, head): 64 tasks ----------
  if (t < 64) {
    const int ep = t >> 5, j = (t >> 2) & 7, h = t & 3;
    const int e0 = ep * EPG;
    float mx = -1e30f;
#pragma unroll
    for (int s = 0; s < 8; s++) {
      if (s == j) continue;
      int e = e0 + s * 7 + (j > s ? j - 1 : j);
      mx = fmaxf(mx, s_alpha[e][h]);
    }
    float sum = 0.f;
#pragma unroll
    for (int s = 0; s < 8; s++) {
      if (s == j) continue;
      int e = e0 + s * 7 + (j > s ? j - 1 : j);
      float ex = __expf(s_alpha[e][h] - mx);
      s_alpha[e][h] = ex;
      sum += ex;
    }
    float inv = 1.f / sum;
#pragma unroll
    for (int s = 0; s < 8; s++) {
      if (s == j) continue;
      int e = e0 + s * 7 + (j > s ? j - 1 : j);
      s_alpha[e][h] *= inv;
    }
  }
  __syncthreads();

  // ---------- Phase 5: aggregate, mean heads, +bias, ReLU -> h_gnn bf16 (256 tasks) ----------
  {
    const int ep = t >> 7, jj = (t >> 4) & 7, dq = t & 15;
    const int a16 = ep * 8 + jj;
    float acc[4] = {0.f, 0.f, 0.f, 0.f};
#pragma unroll 2
    for (int h = 0; h < 4; h++) {
#pragma unroll
      for (int s = 0; s < 8; s++) {
        if (s == jj) continue;
        int e = ep * EPG + s * 7 + (jj > s ? jj - 1 : jj);
        float al = s_alpha[e][h];
        const u16* xp = uXL + (ep * 8 + s) * XLS + h * XHS + dq * 4;
        ushort4 xv = *(const ushort4*)xp;
        acc[0] += al * b2f(xv.x);
        acc[1] += al * b2f(xv.y);
        acc[2] += al * b2f(xv.z);
        acc[3] += al * b2f(xv.w);
      }
    }
    const f32x4 bg = *(const f32x4*)(bias_g + dq * 4);   // global, L2-hot
    u16 pk[4];
#pragma unroll
    for (int c = 0; c < 4; c++) {
      float v = acc[c] * 0.25f + bg[c];
      pk[c] = f2b(v > 0.f ? v : 0.f);
    }
    *(uint2*)&s_hgb[a16 * ABP + dq * 4] = *(uint2*)pk;
  }
  __syncthreads();   // region switch: xl/xr dead, rz/in/hn live

  // ---------- Phase 6 (MFMA): paired gi/gh tiles for 16 agents ----------
  {
    const int arow = L & 15;
    bf16x8 ag0 = *(const bf16x8*)&s_hgb[arow * ABP + q * 8];
    bf16x8 ag1 = *(const bf16x8*)&s_hgb[arow * ABP + 32 + q * 8];
    bf16x8 ah0 = *(const bf16x8*)&s_hidb[arow * ABP + q * 8];
    bf16x8 ah1 = *(const bf16x8*)&s_hidb[arow * ABP + 32 + q * 8];
    const bf16x8* wsBv = (const bf16x8*)wsB;
#pragma unroll
    for (int i = 0; i < 3; i++) {
      const int T6 = w * 3 + i;          // 0..11
      const int Tg = 32 + T6, Th = 44 + T6;
      f32x4 acci = {0.f, 0.f, 0.f, 0.f};
      acci = __builtin_amdgcn_mfma_f32_16x16x32_bf16(ag0, wsBv[(Tg * 2 + 0) * 64 + L], acci, 0, 0, 0);
      acci = __builtin_amdgcn_mfma_f32_16x16x32_bf16(ag1, wsBv[(Tg * 2 + 1) * 64 + L], acci, 0, 0, 0);
      f32x4 acch = {0.f, 0.f, 0.f, 0.f};
      acch = __builtin_amdgcn_mfma_f32_16x16x32_bf16(ah0, wsBv[(Th * 2 + 0) * 64 + L], acch, 0, 0, 0);
      acch = __builtin_amdgcn_mfma_f32_16x16x32_bf16(ah1, wsBv[(Th * 2 + 1) * 64 + L], acch, 0, 0, 0);
      const int col = L & 15;
      const int gc = T6 * 16 + col;      // 0..191
      if (T6 < 8) {                      // r,z gates: store summed
#pragma unroll
        for (int r = 0; r < 4; r++)
          uF[U_RZ + (q * 4 + r) * 128 + gc] = acci[r] + acch[r] + s_bih[gc] + s_bhh[gc];
      } else {                           // n gate: keep separate
#pragma unroll
        for (int r = 0; r < 4; r++) {
          uF[U_IN + (q * 4 + r) * 64 + gc - 128] = acci[r] + s_bih[gc];
          uF[U_HN + (q * 4 + r) * 64 + gc - 128] = acch[r] + s_bhh[gc];
        }
      }
    }
  }
  __syncthreads();

  // ---------- Phase 7+8: GRU gates, write h, in-wave LayerNorm (4 rows/wave) ----------
  {
    const float lng = ln_g[L];   // global, L2-hot
    const float lnb = ln_b[L];
#pragma unroll
    for (int rr = 0; rr < 4; rr++) {
      const int a = w + rr * 4, m = L;   // 0..15
      float rz_r = uF[U_RZ + a * 128 + m];
      float rz_z = uF[U_RZ + a * 128 + 64 + m];
      float inn  = uF[U_IN + a * 64 + m];
      float hn   = uF[U_HN + a * 64 + m];
      float hid  = hidden[(b * NAGB + a) * MDIM + m];  // global re-read, coalesced
      float r = 1.f / (1.f + __expf(-rz_r));
      float z = 1.f / (1.f + __expf(-rz_z));
      float xg = inn + r * hn;
      xg = fminf(fmaxf(xg, -20.f), 20.f);
      float e2 = __expf(2.f * xg);
      float n = (e2 - 1.f) / (e2 + 1.f);
      float hv = (1.f - z) * n + z * hid;
      d_out[NTOT * NACT + (b * NAGB + a) * MDIM + m] = hv;
      float sum = hv;
#pragma unroll
      for (int off = 1; off < 64; off <<= 1) sum += __shfl_xor(sum, off, 64);
      float mu = sum * (1.f / 64.f);
      float dv = hv - mu;
      float s2 = dv * dv;
#pragma unroll
      for (int off = 1; off < 64; off <<= 1) s2 += __shfl_xor(s2, off, 64);
      float var = s2 * (1.f / 64.f);
      uF[U_LN + a * 68 + m] = dv * rsqrtf(var + 1e-5f) * lng + lnb;
    }
  }
  __syncthreads();

  // ---------- Phase 9: q = hln @ Wq^T + bq (160 tasks) ----------
  if (t < NAGB * NACT) {
    const int a = t / NACT, o = t % NACT;
    float acc = bq[o];
    const float4* lv = (const float4*)(uF + U_LN + a * 68);
    const float4* wv = (const float4*)(Wq + o * 64);
#pragma unroll 4
    for (int kq = 0; kq < 16; kq++) {
      float4 l4 = lv[kq], w4 = wv[kq];
      acc += l4.x * w4.x + l4.y * w4.y + l4.z * w4.z + l4.w * w4.w;
    }
    d_out[(b * NAGB + a) * NACT + o] = acc;
  }
}

extern "C" void kernel_launch(void* const* d_in, const int* in_sizes, int n_in,
                              void* d_out, int out_size, void* d_ws, size_t ws_size,
                              hipStream_t stream) {
  const int N  = in_sizes[0] / FIN;   // 32768
  const int Bn = N / NAGB;            // 2048 two-episode blocks
  u16* wsB = (u16*)d_ws;              // 56*2*64*8 bf16 = 112 KiB

  prep_weights<<<28, 256, 0, stream>>>(
      (const float*)d_in[4],   // Wl
      (const float*)d_in[6],   // Wr
      (const float*)d_in[12],  // W_ih
      (const float*)d_in[13],  // W_hh
      wsB);

  gnn_rnn_kernel<<<Bn, 256, 0, stream>>>(
      (const float*)d_in[0], (const float*)d_in[1], (const float*)d_in[2],
      (const float*)d_in[5],   // bl
      (const float*)d_in[7],   // br
      (const float*)d_in[8],   // We
      (const float*)d_in[9],   // be
      (const float*)d_in[10],  // att
      (const float*)d_in[11],  // bias_g
      (const float*)d_in[14],  // b_ih
      (const float*)d_in[15],  // b_hh
      (const float*)d_in[16], (const float*)d_in[17],  // ln_g, ln_b
      (const float*)d_in[18], (const float*)d_in[19],  // Wq, bq
      wsB, (float*)d_out);
}

// Round 11
// 154.055 us; speedup vs baseline: 3.4424x; 1.0209x over previous
//
#include <hip/hip_runtime.h>

typedef unsigned short u16;
typedef __attribute__((ext_vector_type(8))) short bf16x8;
typedef __attribute__((ext_vector_type(4))) float f32x4;

#define NAG 8      // agents per episode
#define NAGB 16    // agents per block (2 episodes)
#define FIN 64
#define MDIM 64
#define NACT 10
#define EPG 56     // edges per episode = 8*7
#define NTOT 32768 // B*A
#define ABP 72     // padded bf16 A-row (144 B)
#define XLS 296    // u16 stride per agent row of xl/xr (148 words ≡ 20 mod 32)
#define XHS 72     // u16 stride per head within a row (36 words ≡ 4 mod 32)

// union region (18944 B):
//  phases 2-5: bf16 xl (16*296 u16 = 9472 B) + xr (9472 B)
//  phases 6-9: f32 rz[16][128] (8192 B) + f32 hn[16][64] (4096 B)
//              + f32 ln[16][68] (4352 B) + bf16 inn[16][64] (2048 B) = 18688 B
#define U_XR  4736           // u16 offset of xr
#define U_RZ  0              // f32 idx
#define U_HN  2048           // f32 idx (byte 8192)
#define U_LN  3072           // f32 idx (byte 12288)
#define U_INB 8320           // u16 idx (byte 16640)

__device__ __forceinline__ float b2f(u16 u) {
  return __uint_as_float(((unsigned int)u) << 16);
}
__device__ __forceinline__ u16 f2b(float f) {
  unsigned int x = __float_as_uint(f);
  unsigned int r = x + 0x7fffu + ((x >> 16) & 1u);   // RNE; values finite
  return (u16)(r >> 16);
}
__device__ __forceinline__ void b8tov(bf16x8 v, f32x4& lo, f32x4& hi) {
#pragma unroll
  for (int c = 0; c < 4; c++) { lo[c] = b2f((u16)v[c]); hi[c] = b2f((u16)v[c + 4]); }
}

// ---------- pre-kernel: repack Wl/Wr/W_ih/W_hh into bf16 B-fragment order ----------
__global__ __launch_bounds__(256) void prep_weights(
    const float* __restrict__ Wl, const float* __restrict__ Wr,
    const float* __restrict__ Wih, const float* __restrict__ Whh,
    u16* __restrict__ wsB)
{
  const int idx = blockIdx.x * 256 + threadIdx.x;   // 0 .. 56*2*64-1
  if (idx >= 56 * 2 * 64) return;
  const int L  = idx & 63;
  const int ks = (idx >> 6) & 1;
  const int T  = idx >> 7;
  const float* W; int row0;
  if      (T < 16) { W = Wl;  row0 = T * 16; }
  else if (T < 32) { W = Wr;  row0 = (T - 16) * 16; }
  else if (T < 44) { W = Wih; row0 = (T - 32) * 16; }
  else             { W = Whh; row0 = (T - 44) * 16; }
  const int row = row0 + (L & 15);
  const int k0  = ks * 32 + (L >> 4) * 8;
  u16 v[8];
#pragma unroll
  for (int j = 0; j < 8; j++) v[j] = f2b(W[row * 64 + k0 + j]);
  *(bf16x8*)(wsB + (size_t)idx * 8) = *(bf16x8*)v;
}

__global__ __launch_bounds__(256, 4) void gnn_rnn_kernel(
    const float* __restrict__ x, const float* __restrict__ edge_attr,
    const float* __restrict__ hidden,
    const float* __restrict__ bl, const float* __restrict__ br,
    const float* __restrict__ We, const float* __restrict__ be,
    const float* __restrict__ att, const float* __restrict__ bias_g,
    const float* __restrict__ b_ih, const float* __restrict__ b_hh,
    const float* __restrict__ ln_g, const float* __restrict__ ln_b,
    const float* __restrict__ Wq, const float* __restrict__ bq,
    const u16* __restrict__ wsB,
    float* __restrict__ d_out)
{
  __shared__ __align__(16) char uraw[18944];
  __shared__ __align__(16) u16 s_xb[NAGB * ABP];    // x bf16 A-frags (16 agents)
  __shared__ __align__(16) u16 s_hidb[NAGB * ABP];  // hidden bf16 A-frags
  __shared__ __align__(16) u16 s_hgb[NAGB * ABP];   // h_gnn bf16 A-frags
  __shared__ float s_ea[2 * EPG * 3];
  __shared__ __align__(16) u16 s_w0b[288], s_w1b[288], s_w2b[288], s_beb[288], s_attb[288];
  __shared__ float s_alpha[2 * EPG][4];

  u16*   uXL  = (u16*)uraw;
  u16*   uXR  = (u16*)uraw + U_XR;
  u16*   uInn = (u16*)uraw + U_INB;
  float* uF   = (float*)uraw;

  const int t = threadIdx.x;
  const int b = blockIdx.x;    // 2-episode group
  const int L = t & 63;        // lane
  const int w = t >> 6;        // wave id 0..3
  const int q = L >> 4;        // quad within wave

  // ---------- Phase 1: stage inputs + small weights ----------
  {
    const float* xb = x + b * (NAGB * FIN);
    const float* hb = hidden + b * (NAGB * MDIM);
#pragma unroll
    for (int i = t; i < NAGB * FIN; i += 256) {
      const int a = i >> 6, m = i & 63;
      s_xb[a * ABP + m] = f2b(xb[i]);
      s_hidb[a * ABP + m] = f2b(hb[i]);
    }
    const float* eb = edge_attr + b * (2 * EPG * 3);
    for (int i = t; i < 2 * EPG * 3; i += 256) s_ea[i] = eb[i];
    {
      const int h = t >> 6, d = t & 63, idx = h * XHS + d;
      s_beb[idx]  = f2b(be[t]);
      s_attb[idx] = f2b(att[t]);
      s_w0b[idx]  = f2b(We[t * 3]);
      s_w1b[idx]  = f2b(We[t * 3 + 1]);
      s_w2b[idx]  = f2b(We[t * 3 + 2]);
    }
  }
  __syncthreads();

  // ---------- Phase 2 (MFMA): xl/xr for 16 agents (all tile rows valid) ----------
  {
    const int arow = L & 15;
    bf16x8 af0 = *(const bf16x8*)&s_xb[arow * ABP + q * 8];
    bf16x8 af1 = *(const bf16x8*)&s_xb[arow * ABP + 32 + q * 8];
    const bf16x8* wsBv = (const bf16x8*)wsB;
#pragma unroll 4
    for (int i = 0; i < 8; i++) {
      const int T = w * 8 + i;
      f32x4 acc = {0.f, 0.f, 0.f, 0.f};
      acc = __builtin_amdgcn_mfma_f32_16x16x32_bf16(af0, wsBv[(T * 2 + 0) * 64 + L], acc, 0, 0, 0);
      acc = __builtin_amdgcn_mfma_f32_16x16x32_bf16(af1, wsBv[(T * 2 + 1) * 64 + L], acc, 0, 0, 0);
      const int col = L & 15;
      const int Tm = T & 15;
      const int h = Tm >> 2, d = (Tm & 3) * 16 + col;
      const int gc = Tm * 16 + col;
      if (T < 16) {
        const float bias = bl[gc];             // global, L2-hot
#pragma unroll
        for (int r = 0; r < 4; r++)
          uXL[(q * 4 + r) * XLS + h * XHS + d] = f2b(acc[r] + bias);
      } else {
        const float bias = br[gc];             // global, L2-hot
#pragma unroll
        for (int r = 0; r < 4; r++)
          uXR[(q * 4 + r) * XLS + h * XHS + d] = f2b(acc[r] + bias);
      }
    }
  }
  __syncthreads();

  // ---------- Phase 3: edge logits, vectorized f32x4 (packed-f32 friendly) ----------
  for (int ep = 0; ep < 2; ep++) {
    if (t < EPG * 4) {
      const int e = t % 56, h = t / 56;
      const int s = e / 7, k = e % 7;
      const int j = k + (k >= s ? 1 : 0);   // dst agent
      const int eg = ep * EPG + e;
      const float ea0 = s_ea[eg * 3], ea1 = s_ea[eg * 3 + 1], ea2 = s_ea[eg * 3 + 2];
      const u16* xlp = uXL + (ep * 8 + s) * XLS + h * XHS;
      const u16* xrp = uXR + (ep * 8 + j) * XLS + h * XHS;
      const u16* w0p = s_w0b + h * XHS;
      const u16* w1p = s_w1b + h * XHS;
      const u16* w2p = s_w2b + h * XHS;
      const u16* bep = s_beb + h * XHS;
      const u16* atp = s_attb + h * XHS;
      f32x4 lgv = {0.f, 0.f, 0.f, 0.f};
#pragma unroll 2
      for (int kq = 0; kq < 8; kq++) {
        f32x4 xlL, xlH, xrL, xrH, w0L, w0H, w1L, w1H, w2L, w2H, bbL, bbH, atL, atH;
        b8tov(*(const bf16x8*)(xlp + kq * 8), xlL, xlH);
        b8tov(*(const bf16x8*)(xrp + kq * 8), xrL, xrH);
        b8tov(*(const bf16x8*)(w0p + kq * 8), w0L, w0H);
        b8tov(*(const bf16x8*)(w1p + kq * 8), w1L, w1H);
        b8tov(*(const bf16x8*)(w2p + kq * 8), w2L, w2H);
        b8tov(*(const bf16x8*)(bep + kq * 8), bbL, bbH);
        b8tov(*(const bf16x8*)(atp + kq * 8), atL, atH);
        f32x4 mL = xlL + xrL + bbL + w0L * ea0 + w1L * ea1 + w2L * ea2;
        f32x4 mH = xlH + xrH + bbH + w0H * ea0 + w1H * ea1 + w2H * ea2;
#pragma unroll
        for (int c = 0; c < 4; c++) {
          mL[c] = fmaxf(mL[c], 0.2f * mL[c]);
          mH[c] = fmaxf(mH[c], 0.2f * mH[c]);
        }
        lgv += mL * atL + mH * atH;
      }
      s_alpha[eg][h] = lgv[0] + lgv[1] + lgv[2] + lgv[3];
    }
  }
  __syncthreads();

  // ---------- Phase 4: softmax per (episode, dst, head): 64 tasks ----------
  if (t < 64) {
    const int ep = t >> 5, j = (t >> 2) & 7, h = t & 3;
    const int e0 = ep * EPG;
    float mx = -1e30f;
#pragma unroll
    for (int s = 0; s < 8; s++) {
      if (s == j) continue;
      int e = e0 + s * 7 + (j > s ? j - 1 : j);
      mx = fmaxf(mx, s_alpha[e][h]);
    }
    float sum = 0.f;
#pragma unroll
    for (int s = 0; s < 8; s++) {
      if (s == j) continue;
      int e = e0 + s * 7 + (j > s ? j - 1 : j);
      float ex = __expf(s_alpha[e][h] - mx);
      s_alpha[e][h] = ex;
      sum += ex;
    }
    float inv = 1.f / sum;
#pragma unroll
    for (int s = 0; s < 8; s++) {
      if (s == j) continue;
      int e = e0 + s * 7 + (j > s ? j - 1 : j);
      s_alpha[e][h] *= inv;
    }
  }
  __syncthreads();

  // ---------- Phase 5: aggregate, mean heads, +bias, ReLU -> h_gnn bf16 (256 tasks) ----------
  {
    const int ep = t >> 7, jj = (t >> 4) & 7, dq = t & 15;
    const int a16 = ep * 8 + jj;
    float acc[4] = {0.f, 0.f, 0.f, 0.f};
#pragma unroll 2
    for (int h = 0; h < 4; h++) {
#pragma unroll
      for (int s = 0; s < 8; s++) {
        if (s == jj) continue;
        int e = ep * EPG + s * 7 + (jj > s ? jj - 1 : jj);
        float al = s_alpha[e][h];
        const u16* xp = uXL + (ep * 8 + s) * XLS + h * XHS + dq * 4;
        ushort4 xv = *(const ushort4*)xp;
        acc[0] += al * b2f(xv.x);
        acc[1] += al * b2f(xv.y);
        acc[2] += al * b2f(xv.z);
        acc[3] += al * b2f(xv.w);
      }
    }
    const f32x4 bg = *(const f32x4*)(bias_g + dq * 4);   // global, L2-hot
    u16 pk[4];
#pragma unroll
    for (int c = 0; c < 4; c++) {
      float v = acc[c] * 0.25f + bg[c];
      pk[c] = f2b(v > 0.f ? v : 0.f);
    }
    *(uint2*)&s_hgb[a16 * ABP + dq * 4] = *(uint2*)pk;
  }
  __syncthreads();   // region switch: xl/xr dead, rz/hn/inn live

  // ---------- Phase 6 (MFMA): paired gi/gh tiles for 16 agents ----------
  {
    const int arow = L & 15;
    bf16x8 ag0 = *(const bf16x8*)&s_hgb[arow * ABP + q * 8];
    bf16x8 ag1 = *(const bf16x8*)&s_hgb[arow * ABP + 32 + q * 8];
    bf16x8 ah0 = *(const bf16x8*)&s_hidb[arow * ABP + q * 8];
    bf16x8 ah1 = *(const bf16x8*)&s_hidb[arow * ABP + 32 + q * 8];
    const bf16x8* wsBv = (const bf16x8*)wsB;
#pragma unroll
    for (int i = 0; i < 3; i++) {
      const int T6 = w * 3 + i;          // 0..11
      const int Tg = 32 + T6, Th = 44 + T6;
      f32x4 acci = {0.f, 0.f, 0.f, 0.f};
      acci = __builtin_amdgcn_mfma_f32_16x16x32_bf16(ag0, wsBv[(Tg * 2 + 0) * 64 + L], acci, 0, 0, 0);
      acci = __builtin_amdgcn_mfma_f32_16x16x32_bf16(ag1, wsBv[(Tg * 2 + 1) * 64 + L], acci, 0, 0, 0);
      f32x4 acch = {0.f, 0.f, 0.f, 0.f};
      acch = __builtin_amdgcn_mfma_f32_16x16x32_bf16(ah0, wsBv[(Th * 2 + 0) * 64 + L], acch, 0, 0, 0);
      acch = __builtin_amdgcn_mfma_f32_16x16x32_bf16(ah1, wsBv[(Th * 2 + 1) * 64 + L], acch, 0, 0, 0);
      const int col = L & 15;
      const int gc = T6 * 16 + col;      // 0..191
      if (T6 < 8) {                      // r,z gates: store summed (+both biases, L2-hot)
        const float bsum = b_ih[gc] + b_hh[gc];
#pragma unroll
        for (int r = 0; r < 4; r++)
          uF[U_RZ + (q * 4 + r) * 128 + gc] = acci[r] + acch[r] + bsum;
      } else {                           // n gate: inn bf16, hn f32
        const float bi = b_ih[gc], bh = b_hh[gc];
#pragma unroll
        for (int r = 0; r < 4; r++) {
          uInn[(q * 4 + r) * 64 + gc - 128] = f2b(acci[r] + bi);
          uF[U_HN + (q * 4 + r) * 64 + gc - 128] = acch[r] + bh;
        }
      }
    }
  }
  __syncthreads();

  // ---------- Phase 7+8: GRU gates, write h, in-wave LayerNorm (4 rows/wave) ----------
  {
    const float lng = ln_g[L];   // global, L2-hot
    const float lnb = ln_b[L];
#pragma unroll
    for (int rr = 0; rr < 4; rr++) {
      const int a = w + rr * 4, m = L;   // 0..15
      float rz_r = uF[U_RZ + a * 128 + m];
      float rz_z = uF[U_RZ + a * 128 + 64 + m];
      float inn  = b2f(uInn[a * 64 + m]);
      float hn   = uF[U_HN + a * 64 + m];
      float hid  = hidden[(b * NAGB + a) * MDIM + m];  // global re-read, coalesced
      float r = 1.f / (1.f + __expf(-rz_r));
      float z = 1.f / (1.f + __expf(-rz_z));
      float xg = inn + r * hn;
      xg = fminf(fmaxf(xg, -20.f), 20.f);
      float e2 = __expf(2.f * xg);
      float n = (e2 - 1.f) / (e2 + 1.f);
      float hv = (1.f - z) * n + z * hid;
      d_out[NTOT * NACT + (b * NAGB + a) * MDIM + m] = hv;
      float sum = hv;
#pragma unroll
      for (int off = 1; off < 64; off <<= 1) sum += __shfl_xor(sum, off, 64);
      float mu = sum * (1.f / 64.f);
      float dv = hv - mu;
      float s2 = dv * dv;
#pragma unroll
      for (int off = 1; off < 64; off <<= 1) s2 += __shfl_xor(s2, off, 64);
      float var = s2 * (1.f / 64.f);
      uF[U_LN + a * 68 + m] = dv * rsqrtf(var + 1e-5f) * lng + lnb;
    }
  }
  __syncthreads();

  // ---------- Phase 9: q = hln @ Wq^T + bq (160 tasks) ----------
  if (t < NAGB * NACT) {
    const int a = t / NACT, o = t % NACT;
    float acc = bq[o];
    const float4* lv = (const float4*)(uF + U_LN + a * 68);
    const float4* wv = (const float4*)(Wq + o * 64);
#pragma unroll 4
    for (int kq = 0; kq < 16; kq++) {
      float4 l4 = lv[kq], w4 = wv[kq];
      acc += l4.x * w4.x + l4.y * w4.y + l4.z * w4.z + l4.w * w4.w;
    }
    d_out[(b * NAGB + a) * NACT + o] = acc;
  }
}

extern "C" void kernel_launch(void* const* d_in, const int* in_sizes, int n_in,
                              void* d_out, int out_size, void* d_ws, size_t ws_size,
                              hipStream_t stream) {
  const int N  = in_sizes[0] / FIN;   // 32768
  const int Bn = N / NAGB;            // 2048 two-episode blocks
  u16* wsB = (u16*)d_ws;              // 56*2*64*8 bf16 = 112 KiB

  prep_weights<<<28, 256, 0, stream>>>(
      (const float*)d_in[4],   // Wl
      (const float*)d_in[6],   // Wr
      (const float*)d_in[12],  // W_ih
      (const float*)d_in[13],  // W_hh
      wsB);

  gnn_rnn_kernel<<<Bn, 256, 0, stream>>>(
      (const float*)d_in[0], (const float*)d_in[1], (const float*)d_in[2],
      (const float*)d_in[5],   // bl
      (const float*)d_in[7],   // br
      (const float*)d_in[8],   // We
      (const float*)d_in[9],   // be
      (const float*)d_in[10],  // att
      (const float*)d_in[11],  // bias_g
      (const float*)d_in[14],  // b_ih
      (const float*)d_in[15],  // b_hh
      (const float*)d_in[16], (const float*)d_in[17],  // ln_g, ln_b
      (const float*)d_in[18], (const float*)d_in[19],  // Wq, bq
      wsB, (float*)d_out);
}

// Round 12
// 151.235 us; speedup vs baseline: 3.5066x; 1.0187x over previous
//
#include <hip/hip_runtime.h>

typedef unsigned short u16;
typedef __attribute__((ext_vector_type(8))) short bf16x8;
typedef __attribute__((ext_vector_type(4))) float f32x4;

#define NAG 8      // agents per episode
#define NAGB 16    // agents per block (2 episodes)
#define FIN 64
#define MDIM 64
#define NACT 10
#define EPG 56     // edges per episode = 8*7
#define NTOT 32768 // B*A
#define ABP 72     // padded bf16 A-row (144 B)
#define XLS 296    // u16 stride per agent row of xl/xr (148 words ≡ 20 mod 32)
#define XHS 72     // u16 stride per head within a row (36 words ≡ 4 mod 32)

// union region (18944 B):
//  phases 2-5: bf16 xl (16*296 u16 = 9472 B) + xr (9472 B)
//  phases 6-9: f32 rz[16][128] + f32 hn[16][64] + f32 ln[16][68] + bf16 inn[16][64]
#define U_XR  4736           // u16 offset of xr
#define U_RZ  0              // f32 idx
#define U_HN  2048           // f32 idx
#define U_LN  3072           // f32 idx
#define U_INB 8320           // u16 idx

__device__ __forceinline__ float b2f(u16 u) {
  return __uint_as_float(((unsigned int)u) << 16);
}
__device__ __forceinline__ u16 f2b(float f) {
  unsigned int x = __float_as_uint(f);
  unsigned int r = x + 0x7fffu + ((x >> 16) & 1u);   // RNE; values finite
  return (u16)(r >> 16);
}
__device__ __forceinline__ void b8tov(bf16x8 v, f32x4& lo, f32x4& hi) {
#pragma unroll
  for (int c = 0; c < 4; c++) { lo[c] = b2f((u16)v[c]); hi[c] = b2f((u16)v[c + 4]); }
}

// ---------- pre-kernel: repack Wl/Wr/W_ih/W_hh into bf16 B-fragment order ----------
__global__ __launch_bounds__(256) void prep_weights(
    const float* __restrict__ Wl, const float* __restrict__ Wr,
    const float* __restrict__ Wih, const float* __restrict__ Whh,
    u16* __restrict__ wsB)
{
  const int idx = blockIdx.x * 256 + threadIdx.x;   // 0 .. 56*2*64-1
  if (idx >= 56 * 2 * 64) return;
  const int L  = idx & 63;
  const int ks = (idx >> 6) & 1;
  const int T  = idx >> 7;
  const float* W; int row0;
  if      (T < 16) { W = Wl;  row0 = T * 16; }
  else if (T < 32) { W = Wr;  row0 = (T - 16) * 16; }
  else if (T < 44) { W = Wih; row0 = (T - 32) * 16; }
  else             { W = Whh; row0 = (T - 44) * 16; }
  const int row = row0 + (L & 15);
  const int k0  = ks * 32 + (L >> 4) * 8;
  u16 v[8];
#pragma unroll
  for (int j = 0; j < 8; j++) v[j] = f2b(W[row * 64 + k0 + j]);
  *(bf16x8*)(wsB + (size_t)idx * 8) = *(bf16x8*)v;
}

__global__ __launch_bounds__(256, 4) void gnn_rnn_kernel(
    const float* __restrict__ x, const float* __restrict__ edge_attr,
    const float* __restrict__ hidden,
    const float* __restrict__ bl, const float* __restrict__ br,
    const float* __restrict__ We, const float* __restrict__ be,
    const float* __restrict__ att, const float* __restrict__ bias_g,
    const float* __restrict__ b_ih, const float* __restrict__ b_hh,
    const float* __restrict__ ln_g, const float* __restrict__ ln_b,
    const float* __restrict__ Wq, const float* __restrict__ bq,
    const u16* __restrict__ wsB,
    float* __restrict__ d_out)
{
  __shared__ __align__(16) char uraw[18944];
  __shared__ __align__(16) u16 s_xb[NAGB * ABP];    // x bf16 A-frags (16 agents)
  __shared__ __align__(16) u16 s_hidb[NAGB * ABP];  // hidden bf16 A-frags
  __shared__ __align__(16) u16 s_hgb[NAGB * ABP];   // h_gnn bf16 A-frags
  __shared__ float s_ea[2 * EPG * 3];
  __shared__ __align__(16) u16 s_blb[256], s_brb[256];
  __shared__ __align__(16) u16 s_w0b[288], s_w1b[288], s_w2b[288], s_beb[288], s_attb[288];
  __shared__ float s_alpha[2 * EPG][4];

  u16*   uXL  = (u16*)uraw;
  u16*   uXR  = (u16*)uraw + U_XR;
  u16*   uInn = (u16*)uraw + U_INB;
  float* uF   = (float*)uraw;

  const int t = threadIdx.x;
  const int b = blockIdx.x;    // 2-episode group
  const int L = t & 63;        // lane
  const int w = t >> 6;        // wave id 0..3
  const int q = L >> 4;        // quad within wave

  // ---------- Phase 1: stage inputs + small weights ----------
  {
    const float* xb = x + b * (NAGB * FIN);
    const float* hb = hidden + b * (NAGB * MDIM);
#pragma unroll
    for (int i = t; i < NAGB * FIN; i += 256) {
      const int a = i >> 6, m = i & 63;
      s_xb[a * ABP + m] = f2b(xb[i]);
      s_hidb[a * ABP + m] = f2b(hb[i]);
    }
    const float* eb = edge_attr + b * (2 * EPG * 3);
    for (int i = t; i < 2 * EPG * 3; i += 256) s_ea[i] = eb[i];
    s_blb[t] = f2b(bl[t]);  s_brb[t] = f2b(br[t]);
    {
      const int h = t >> 6, d = t & 63, idx = h * XHS + d;
      s_beb[idx]  = f2b(be[t]);
      s_attb[idx] = f2b(att[t]);
      s_w0b[idx]  = f2b(We[t * 3]);
      s_w1b[idx]  = f2b(We[t * 3 + 1]);
      s_w2b[idx]  = f2b(We[t * 3 + 2]);
    }
  }
  __syncthreads();

  // ---------- Phase 2 (MFMA): xl/xr for 16 agents ----------
  {
    const int arow = L & 15;
    bf16x8 af0 = *(const bf16x8*)&s_xb[arow * ABP + q * 8];
    bf16x8 af1 = *(const bf16x8*)&s_xb[arow * ABP + 32 + q * 8];
    const bf16x8* wsBv = (const bf16x8*)wsB;
#pragma unroll 4
    for (int i = 0; i < 8; i++) {
      const int T = w * 8 + i;
      f32x4 acc = {0.f, 0.f, 0.f, 0.f};
      acc = __builtin_amdgcn_mfma_f32_16x16x32_bf16(af0, wsBv[(T * 2 + 0) * 64 + L], acc, 0, 0, 0);
      acc = __builtin_amdgcn_mfma_f32_16x16x32_bf16(af1, wsBv[(T * 2 + 1) * 64 + L], acc, 0, 0, 0);
      const int col = L & 15;
      const int Tm = T & 15;
      const int h = Tm >> 2, d = (Tm & 3) * 16 + col;
      const int gc = Tm * 16 + col;
      if (T < 16) {
        const float bias = b2f(s_blb[gc]);
#pragma unroll
        for (int r = 0; r < 4; r++)
          uXL[(q * 4 + r) * XLS + h * XHS + d] = f2b(acc[r] + bias);
      } else {
        const float bias = b2f(s_brb[gc]);
#pragma unroll
        for (int r = 0; r < 4; r++)
          uXR[(q * 4 + r) * XLS + h * XHS + d] = f2b(acc[r] + bias);
      }
    }
  }
  __syncthreads();

  // ---------- Phase 3: edge logits — BOTH episodes in one pass (weights unpacked once) ----------
  if (t < EPG * 4) {
    const int e = t % 56, h = t / 56;
    const int s = e / 7, k = e % 7;
    const int j = k + (k >= s ? 1 : 0);   // dst agent
    const float ea00 = s_ea[e * 3], ea01 = s_ea[e * 3 + 1], ea02 = s_ea[e * 3 + 2];
    const float ea10 = s_ea[(EPG + e) * 3], ea11 = s_ea[(EPG + e) * 3 + 1],
                ea12 = s_ea[(EPG + e) * 3 + 2];
    const u16* xlp0 = uXL + s * XLS + h * XHS;
    const u16* xrp0 = uXR + j * XLS + h * XHS;
    const u16* xlp1 = uXL + (8 + s) * XLS + h * XHS;
    const u16* xrp1 = uXR + (8 + j) * XLS + h * XHS;
    const u16* w0p = s_w0b + h * XHS;
    const u16* w1p = s_w1b + h * XHS;
    const u16* w2p = s_w2b + h * XHS;
    const u16* bep = s_beb + h * XHS;
    const u16* atp = s_attb + h * XHS;
    f32x4 lg0 = {0.f, 0.f, 0.f, 0.f};
    f32x4 lg1 = {0.f, 0.f, 0.f, 0.f};
#pragma unroll 1
    for (int kq = 0; kq < 8; kq++) {
      f32x4 w0L, w0H, w1L, w1H, w2L, w2H, bbL, bbH, atL, atH;
      b8tov(*(const bf16x8*)(w0p + kq * 8), w0L, w0H);
      b8tov(*(const bf16x8*)(w1p + kq * 8), w1L, w1H);
      b8tov(*(const bf16x8*)(w2p + kq * 8), w2L, w2H);
      b8tov(*(const bf16x8*)(bep + kq * 8), bbL, bbH);
      b8tov(*(const bf16x8*)(atp + kq * 8), atL, atH);
      {
        f32x4 xlL, xlH, xrL, xrH;
        b8tov(*(const bf16x8*)(xlp0 + kq * 8), xlL, xlH);
        b8tov(*(const bf16x8*)(xrp0 + kq * 8), xrL, xrH);
        f32x4 mL = xlL + xrL + bbL + w0L * ea00 + w1L * ea01 + w2L * ea02;
        f32x4 mH = xlH + xrH + bbH + w0H * ea00 + w1H * ea01 + w2H * ea02;
#pragma unroll
        for (int c = 0; c < 4; c++) {
          mL[c] = fmaxf(mL[c], 0.2f * mL[c]);
          mH[c] = fmaxf(mH[c], 0.2f * mH[c]);
        }
        lg0 += mL * atL + mH * atH;
      }
      {
        f32x4 xlL, xlH, xrL, xrH;
        b8tov(*(const bf16x8*)(xlp1 + kq * 8), xlL, xlH);
        b8tov(*(const bf16x8*)(xrp1 + kq * 8), xrL, xrH);
        f32x4 mL = xlL + xrL + bbL + w0L * ea10 + w1L * ea11 + w2L * ea12;
        f32x4 mH = xlH + xrH + bbH + w0H * ea10 + w1H * ea11 + w2H * ea12;
#pragma unroll
        for (int c = 0; c < 4; c++) {
          mL[c] = fmaxf(mL[c], 0.2f * mL[c]);
          mH[c] = fmaxf(mH[c], 0.2f * mH[c]);
        }
        lg1 += mL * atL + mH * atH;
      }
    }
    s_alpha[e][h]       = lg0[0] + lg0[1] + lg0[2] + lg0[3];
    s_alpha[EPG + e][h] = lg1[0] + lg1[1] + lg1[2] + lg1[3];
  }
  __syncthreads();

  // ---------- Phase 4: softmax per (episode, dst, head): 64 tasks ----------
  if (t < 64) {
    const int ep = t >> 5, j = (t >> 2) & 7, h = t & 3;
    const int e0 = ep * EPG;
    float mx = -1e30f;
#pragma unroll
    for (int s = 0; s < 8; s++) {
      if (s == j) continue;
      int e = e0 + s * 7 + (j > s ? j - 1 : j);
      mx = fmaxf(mx, s_alpha[e][h]);
    }
    float sum = 0.f;
#pragma unroll
    for (int s = 0; s < 8; s++) {
      if (s == j) continue;
      int e = e0 + s * 7 + (j > s ? j - 1 : j);
      float ex = __expf(s_alpha[e][h] - mx);
      s_alpha[e][h] = ex;
      sum += ex;
    }
    float inv = 1.f / sum;
#pragma unroll
    for (int s = 0; s < 8; s++) {
      if (s == j) continue;
      int e = e0 + s * 7 + (j > s ? j - 1 : j);
      s_alpha[e][h] *= inv;
    }
  }
  __syncthreads();

  // ---------- Phase 5: aggregate, mean heads, +bias, ReLU -> h_gnn bf16 ----------
  {
    const int ep = t >> 7, jj = (t >> 4) & 7, dq = t & 15;
    const int a16 = ep * 8 + jj;
    float acc[4] = {0.f, 0.f, 0.f, 0.f};
#pragma unroll 2
    for (int h = 0; h < 4; h++) {
#pragma unroll
      for (int s = 0; s < 8; s++) {
        if (s == jj) continue;
        int e = ep * EPG + s * 7 + (jj > s ? jj - 1 : jj);
        float al = s_alpha[e][h];
        const u16* xp = uXL + (ep * 8 + s) * XLS + h * XHS + dq * 4;
        ushort4 xv = *(const ushort4*)xp;
        acc[0] += al * b2f(xv.x);
        acc[1] += al * b2f(xv.y);
        acc[2] += al * b2f(xv.z);
        acc[3] += al * b2f(xv.w);
      }
    }
    const f32x4 bg = *(const f32x4*)(bias_g + dq * 4);   // global, L2-hot
    u16 pk[4];
#pragma unroll
    for (int c = 0; c < 4; c++) {
      float v = acc[c] * 0.25f + bg[c];
      pk[c] = f2b(v > 0.f ? v : 0.f);
    }
    *(uint2*)&s_hgb[a16 * ABP + dq * 4] = *(uint2*)pk;
  }
  __syncthreads();   // region switch: xl/xr dead, rz/hn/inn live

  // ---------- Phase 6 (MFMA): paired gi/gh tiles for 16 agents ----------
  {
    const int arow = L & 15;
    bf16x8 ag0 = *(const bf16x8*)&s_hgb[arow * ABP + q * 8];
    bf16x8 ag1 = *(const bf16x8*)&s_hgb[arow * ABP + 32 + q * 8];
    bf16x8 ah0 = *(const bf16x8*)&s_hidb[arow * ABP + q * 8];
    bf16x8 ah1 = *(const bf16x8*)&s_hidb[arow * ABP + 32 + q * 8];
    const bf16x8* wsBv = (const bf16x8*)wsB;
#pragma unroll
    for (int i = 0; i < 3; i++) {
      const int T6 = w * 3 + i;          // 0..11
      const int Tg = 32 + T6, Th = 44 + T6;
      f32x4 acci = {0.f, 0.f, 0.f, 0.f};
      acci = __builtin_amdgcn_mfma_f32_16x16x32_bf16(ag0, wsBv[(Tg * 2 + 0) * 64 + L], acci, 0, 0, 0);
      acci = __builtin_amdgcn_mfma_f32_16x16x32_bf16(ag1, wsBv[(Tg * 2 + 1) * 64 + L], acci, 0, 0, 0);
      f32x4 acch = {0.f, 0.f, 0.f, 0.f};
      acch = __builtin_amdgcn_mfma_f32_16x16x32_bf16(ah0, wsBv[(Th * 2 + 0) * 64 + L], acch, 0, 0, 0);
      acch = __builtin_amdgcn_mfma_f32_16x16x32_bf16(ah1, wsBv[(Th * 2 + 1) * 64 + L], acch, 0, 0, 0);
      const int col = L & 15;
      const int gc = T6 * 16 + col;      // 0..191
      if (T6 < 8) {                      // r,z gates: store summed (+both biases, L2-hot)
        const float bsum = b_ih[gc] + b_hh[gc];
#pragma unroll
        for (int r = 0; r < 4; r++)
          uF[U_RZ + (q * 4 + r) * 128 + gc] = acci[r] + acch[r] + bsum;
      } else {                           // n gate: inn bf16, hn f32
        const float bi = b_ih[gc], bh = b_hh[gc];
#pragma unroll
        for (int r = 0; r < 4; r++) {
          uInn[(q * 4 + r) * 64 + gc - 128] = f2b(acci[r] + bi);
          uF[U_HN + (q * 4 + r) * 64 + gc - 128] = acch[r] + bh;
        }
      }
    }
  }
  __syncthreads();

  // ---------- Phase 7+8: GRU gates, write h, in-wave LayerNorm (4 rows/wave) ----------
  {
    const float lng = ln_g[L];   // global, L2-hot
    const float lnb = ln_b[L];
#pragma unroll
    for (int rr = 0; rr < 4; rr++) {
      const int a = w + rr * 4, m = L;   // 0..15
      float rz_r = uF[U_RZ + a * 128 + m];
      float rz_z = uF[U_RZ + a * 128 + 64 + m];
      float inn  = b2f(uInn[a * 64 + m]);
      float hn   = uF[U_HN + a * 64 + m];
      float hid  = b2f(s_hidb[a * ABP + m]);
      float r = 1.f / (1.f + __expf(-rz_r));
      float z = 1.f / (1.f + __expf(-rz_z));
      float xg = inn + r * hn;
      xg = fminf(fmaxf(xg, -20.f), 20.f);
      float e2 = __expf(2.f * xg);
      float n = (e2 - 1.f) / (e2 + 1.f);
      float hv = (1.f - z) * n + z * hid;
      d_out[NTOT * NACT + (b * NAGB + a) * MDIM + m] = hv;
      float sum = hv;
#pragma unroll
      for (int off = 1; off < 64; off <<= 1) sum += __shfl_xor(sum, off, 64);
      float mu = sum * (1.f / 64.f);
      float dv = hv - mu;
      float s2 = dv * dv;
#pragma unroll
      for (int off = 1; off < 64; off <<= 1) s2 += __shfl_xor(s2, off, 64);
      float var = s2 * (1.f / 64.f);
      uF[U_LN + a * 68 + m] = dv * rsqrtf(var + 1e-5f) * lng + lnb;
    }
  }
  __syncthreads();

  // ---------- Phase 9: q = hln @ Wq^T + bq (160 tasks) ----------
  if (t < NAGB * NACT) {
    const int a = t / NACT, o = t % NACT;
    float acc = bq[o];
    const float4* lv = (const float4*)(uF + U_LN + a * 68);
    const float4* wv = (const float4*)(Wq + o * 64);
#pragma unroll 4
    for (int kq = 0; kq < 16; kq++) {
      float4 l4 = lv[kq], w4 = wv[kq];
      acc += l4.x * w4.x + l4.y * w4.y + l4.z * w4.z + l4.w * w4.w;
    }
    d_out[(b * NAGB + a) * NACT + o] = acc;
  }
}

extern "C" void kernel_launch(void* const* d_in, const int* in_sizes, int n_in,
                              void* d_out, int out_size, void* d_ws, size_t ws_size,
                              hipStream_t stream) {
  const int N  = in_sizes[0] / FIN;   // 32768
  const int Bn = N / NAGB;            // 2048 two-episode blocks
  u16* wsB = (u16*)d_ws;              // 56*2*64*8 bf16 = 112 KiB

  prep_weights<<<28, 256, 0, stream>>>(
      (const float*)d_in[4],   // Wl
      (const float*)d_in[6],   // Wr
      (const float*)d_in[12],  // W_ih
      (const float*)d_in[13],  // W_hh
      wsB);

  gnn_rnn_kernel<<<Bn, 256, 0, stream>>>(
      (const float*)d_in[0], (const float*)d_in[1], (const float*)d_in[2],
      (const float*)d_in[5],   // bl
      (const float*)d_in[7],   // br
      (const float*)d_in[8],   // We
      (const float*)d_in[9],   // be
      (const float*)d_in[10],  // att
      (const float*)d_in[11],  // bias_g
      (const float*)d_in[14],  // b_ih
      (const float*)d_in[15],  // b_hh
      (const float*)d_in[16], (const float*)d_in[17],  // ln_g, ln_b
      (const float*)d_in[18], (const float*)d_in[19],  // Wq, bq
      wsB, (float*)d_out);
}